// Round 1
// baseline (2149.229 us; speedup 1.0000x reference)
//
#include <hip/hip_runtime.h>
#include <math.h>

// RWKV block forward for MI355X — round 0: correct fp32 baseline.
// B=2 T=512 E=1024 H=16 Sh=64 D=1024 F=4096 CHUNK=64
#define T_  512
#define E_  1024
#define BTE 1048576   // B*T*E floats

enum { EPI_NONE=0, EPI_TANH=1, EPI_SILU=2, EPI_RELU2=3, EPI_WLOG=4, EPI_ADDRES=5, EPI_SIGMUL=6 };

// ---------------- LayerNorm over rows of length 1024 ----------------
__global__ __launch_bounds__(256) void ln_rows_k(const float* __restrict__ x,
        const float* __restrict__ sc, const float* __restrict__ bi,
        float* __restrict__ out)
{
    const int row = blockIdx.x;
    const int tid = threadIdx.x;
    const float* xr = x + (size_t)row * E_;
    float4 v = *reinterpret_cast<const float4*>(xr + tid*4);
    float s  = v.x + v.y + v.z + v.w;
    float ss = v.x*v.x + v.y*v.y + v.z*v.z + v.w*v.w;
    #pragma unroll
    for (int off = 32; off > 0; off >>= 1) {
        s  += __shfl_down(s, off);
        ss += __shfl_down(ss, off);
    }
    __shared__ float ps[4], pss[4];
    __shared__ float smu, srstd;
    if ((tid & 63) == 0) { ps[tid>>6] = s; pss[tid>>6] = ss; }
    __syncthreads();
    if (tid == 0) {
        float S  = ps[0]+ps[1]+ps[2]+ps[3];
        float SS = pss[0]+pss[1]+pss[2]+pss[3];
        float mu  = S * (1.f/E_);
        float var = SS * (1.f/E_) - mu*mu;
        smu = mu; srstd = rsqrtf(var + 1e-5f);
    }
    __syncthreads();
    const float mu = smu, rstd = srstd;
    float4 s4 = *reinterpret_cast<const float4*>(sc + tid*4);
    float4 b4 = *reinterpret_cast<const float4*>(bi + tid*4);
    float4 o;
    o.x = (v.x-mu)*rstd*s4.x + b4.x;
    o.y = (v.y-mu)*rstd*s4.y + b4.y;
    o.z = (v.z-mu)*rstd*s4.z + b4.z;
    o.w = (v.w-mu)*rstd*s4.w + b4.w;
    *reinterpret_cast<float4*>(out + (size_t)row*E_ + tid*4) = o;
}

// ---------------- xmix = xn + (shift(xn)-xn)*maa_x ----------------
__global__ __launch_bounds__(256) void mix_x_k(const float* __restrict__ xn,
        const float* __restrict__ maa, float* __restrict__ out)
{
    int idx = blockIdx.x*256 + threadIdx.x;     // < BTE
    int e = idx & 1023;
    int t = (idx >> 10) & 511;
    float xv = xn[idx];
    float prev = t ? xn[idx - E_] : 0.f;
    out[idx] = xv + (prev - xv) * maa[e];
}

// ---------------- channel-mix shift: ak/ar ----------------
__global__ __launch_bounds__(256) void mix_ch_k(const float* __restrict__ xn2,
        const float* __restrict__ maaK, const float* __restrict__ maaR,
        float* __restrict__ ak, float* __restrict__ ar)
{
    int idx = blockIdx.x*256 + threadIdx.x;
    int e = idx & 1023;
    int t = (idx >> 10) & 511;
    float xv = xn2[idx];
    float prev = t ? xn2[idx - E_] : 0.f;
    float sxv = prev - xv;
    ak[idx] = xv + sxv * maaK[e];
    ar[idx] = xv + sxv * maaR[e];
}

// ---------------- mix5: xw/xk/xv/xr/xg from t5 @ W2 (with reshape quirk) ----------------
// m_o[b,t,e] uses t5 lane L=o*2+b -> (b_src=L/5, g_src=L%5)   [faithful (B,5,T,E)->(5,B,T,E)]
__global__ __launch_bounds__(256) void mix5_k(const float* __restrict__ xn,
        const float* __restrict__ t5, const float* __restrict__ W2,
        const float* __restrict__ maaW, const float* __restrict__ maaK,
        const float* __restrict__ maaV, const float* __restrict__ maaR,
        const float* __restrict__ maaG,
        float* __restrict__ xw, float* __restrict__ xk, float* __restrict__ xv,
        float* __restrict__ xr, float* __restrict__ xg)
{
    const int bt = blockIdx.x;
    const int b = bt >> 9, t = bt & 511;
    __shared__ float st5[5][32];
    __shared__ int sgs[5];
    const int tid = threadIdx.x;
    if (tid < 160) {
        int o = tid >> 5, c = tid & 31;
        int L = o*2 + b;
        int bs = L / 5, gs = L - bs*5;
        st5[o][c] = t5[((size_t)(bs*T_ + t))*160 + gs*32 + c];
        if (c == 0) sgs[o] = gs;
    }
    __syncthreads();
    const float* xnrow = xn + (size_t)bt*E_;
    const int g0=sgs[0], g1=sgs[1], g2=sgs[2], g3=sgs[3], g4=sgs[4];
    for (int e = tid; e < E_; e += 256) {
        float xnv = xnrow[e];
        float prev = (t > 0) ? xnrow[e - E_] : 0.f;
        float sxv = prev - xnv;
        float m0=0.f, m1=0.f, m2=0.f, m3=0.f, m4=0.f;
        #pragma unroll 4
        for (int c = 0; c < 32; ++c) {
            float a0 = st5[0][c], a1 = st5[1][c], a2 = st5[2][c], a3 = st5[3][c], a4 = st5[4][c];
            m0 += a0 * W2[((size_t)g0*32 + c)*E_ + e];
            m1 += a1 * W2[((size_t)g1*32 + c)*E_ + e];
            m2 += a2 * W2[((size_t)g2*32 + c)*E_ + e];
            m3 += a3 * W2[((size_t)g3*32 + c)*E_ + e];
            m4 += a4 * W2[((size_t)g4*32 + c)*E_ + e];
        }
        size_t oidx = (size_t)bt*E_ + e;
        xw[oidx] = xnv + sxv*(maaW[e] + m0);
        xk[oidx] = xnv + sxv*(maaK[e] + m1);
        xv[oidx] = xnv + sxv*(maaV[e] + m2);
        xr[oidx] = xnv + sxv*(maaR[e] + m3);
        xg[oidx] = xnv + sxv*(maaG[e] + m4);
    }
}

// ---------------- generic fp32 GEMM: C = epi(A(MxK) @ B(KxN)) ----------------
template<int EPI>
__global__ __launch_bounds__(256) void gemm_k(const float* __restrict__ A,
        const float* __restrict__ B, float* __restrict__ C,
        int M, int N, int K,
        const float* __restrict__ p1, const float* __restrict__ p2)
{
    __shared__ float As[64][20];   // [m][k], pad to 20 for bank spread + 16B align
    __shared__ float Bs[16][64];
    const int tid = threadIdx.x;
    const int tx = tid & 15, ty = tid >> 4;
    const int m0 = blockIdx.y * 64, n0 = blockIdx.x * 64;
    float acc[4][4] = {};
    for (int k0 = 0; k0 < K; k0 += 16) {
        #pragma unroll
        for (int i = 0; i < 4; ++i) {
            int l = tid + i*256;
            int m = l >> 4, kk = l & 15;
            int gm = m0 + m;
            As[m][kk] = (gm < M) ? A[(size_t)gm*K + k0 + kk] : 0.f;
        }
        #pragma unroll
        for (int i = 0; i < 4; ++i) {
            int l = tid + i*256;
            int kk = l >> 6, n = l & 63;
            int gn = n0 + n;
            Bs[kk][n] = (gn < N) ? B[(size_t)(k0+kk)*N + gn] : 0.f;
        }
        __syncthreads();
        #pragma unroll
        for (int kk = 0; kk < 16; kk += 4) {
            float4 a4[4];
            #pragma unroll
            for (int i = 0; i < 4; ++i)
                a4[i] = *reinterpret_cast<const float4*>(&As[ty*4+i][kk]);
            float4 b0 = *reinterpret_cast<const float4*>(&Bs[kk+0][tx*4]);
            float4 b1 = *reinterpret_cast<const float4*>(&Bs[kk+1][tx*4]);
            float4 b2 = *reinterpret_cast<const float4*>(&Bs[kk+2][tx*4]);
            float4 b3 = *reinterpret_cast<const float4*>(&Bs[kk+3][tx*4]);
            #pragma unroll
            for (int i = 0; i < 4; ++i) {
                acc[i][0] += a4[i].x*b0.x + a4[i].y*b1.x + a4[i].z*b2.x + a4[i].w*b3.x;
                acc[i][1] += a4[i].x*b0.y + a4[i].y*b1.y + a4[i].z*b2.y + a4[i].w*b3.y;
                acc[i][2] += a4[i].x*b0.z + a4[i].y*b1.z + a4[i].z*b2.z + a4[i].w*b3.z;
                acc[i][3] += a4[i].x*b0.w + a4[i].y*b1.w + a4[i].z*b2.w + a4[i].w*b3.w;
            }
        }
        __syncthreads();
    }
    #pragma unroll
    for (int i = 0; i < 4; ++i) {
        int gm = m0 + ty*4 + i;
        if (gm >= M) continue;
        #pragma unroll
        for (int j = 0; j < 4; ++j) {
            int gn = n0 + tx*4 + j;
            if (gn >= N) continue;
            size_t idx = (size_t)gm*N + gn;
            float a = acc[i][j];
            float o;
            if (EPI == EPI_NONE)        o = a;
            else if (EPI == EPI_TANH)   o = tanhf(a);
            else if (EPI == EPI_SILU)   o = a / (1.f + expf(-a));
            else if (EPI == EPI_RELU2)  { float r = fmaxf(a, 0.f); o = r*r; }
            else if (EPI == EPI_WLOG) {
                // w = log(clip(softplus(-(time_decay[n] + acc)), 1e-6, 1))
                float z = -(p1[gn] + a);
                float sp = (z > 15.f) ? z : log1pf(expf(z));
                float cl = fminf(fmaxf(sp, 1e-6f), 1.f);
                o = logf(cl);
            }
            else if (EPI == EPI_ADDRES) o = a + p1[idx];
            else /* EPI_SIGMUL */       o = p2[idx] + p1[idx] / (1.f + expf(-a));
            C[idx] = o;
        }
    }
}

// ---------------- chunkwise RWKV scan (factored per-chunk matmul form) ----------------
// Faithful to reference per-step scan:
//   S_c = exp(A_intra[c,k]) (col) * S_{c-1} + akv_c⊗v_c,  akv = exp(Atot-A)·k
//   inter[t,k] = BF[t,k]·( (RD@S0)[t,k] + Σ_{s<t} P[t,s]·VX[s,k] ),  RD = r·exp(Aex)
//   P = RD·KAᵀ;  VX[s,k] = v·exp(-Bcum[s,k]);  BF = exp(Bcum[t,k]-A[t,k]); Bcum = cumsum_t(A)
//   intra[t,k] = Σ_{s<t} Q[t,s]·v[s,k] + udiag[t]·v[t,k],  Q = RD·KAᵀ·exp(-Atot)
//   S_end = exp(Bcum[63,k])·( S0 + KAᵀ@VX )
// On this dataset all decay logs are exactly 0 (softplus≥1.31 clips to 1), so every exp()==1.
__global__ __launch_bounds__(256) void chunkwise_k(
    const float* __restrict__ rb, const float* __restrict__ kb,
    const float* __restrict__ vb, const float* __restrict__ wb,
    const float* __restrict__ faaaa, const float* __restrict__ st_in,
    float* __restrict__ yb, float* __restrict__ st_out)
{
    const int lane = blockIdx.x;          // b*16 + h
    const int b = lane >> 4, h = lane & 15;
    const int tid = threadIdx.x;
    const int LD = 65;

    __shared__ float sS0[64*65];
    __shared__ float sRD[64*65];
    __shared__ float sKA[64*65];
    __shared__ float sV [64*65];
    __shared__ float sA [64*65];   // A_intra; overwritten by BF in phase C
    __shared__ float sPQ[64*65];
    __shared__ float sUD[64];
    __shared__ float sB63[64];     // exp(Bcum[63,k])
    __shared__ float sQS[4][64];

    for (int i = tid; i < 4096; i += 256)
        sS0[(i>>6)*LD + (i&63)] = st_in[(size_t)lane*4096 + i];

    const int jl = tid & 63;
    const int q  = tid >> 6;
    const float u_reg = faaaa[h*64 + jl];
    const size_t base = (size_t)b*T_*E_ + (size_t)h*64;   // + t*1024 + j
    const int tx = tid & 15, ty = tid >> 4;
    __syncthreads();

    for (int nc = 0; nc < 8; ++nc) {
        const int t0 = nc*64;
        // ---- A1: cumsum(wlog) over t within chunk -> sA ----
        {
            float loc[16]; float cum = 0.f;
            #pragma unroll
            for (int c = 0; c < 16; ++c) {
                float wv = wb[base + (size_t)(t0 + q*16 + c)*E_ + jl];
                cum += wv; loc[c] = cum;
            }
            sQS[q][jl] = cum;
            __syncthreads();
            float pre = 0.f;
            for (int qq = 0; qq < q; ++qq) pre += sQS[qq][jl];
            #pragma unroll
            for (int c = 0; c < 16; ++c) sA[(q*16+c)*LD + jl] = loc[c] + pre;
        }
        __syncthreads();
        // ---- A2: load r,k,v; RD/KA transforms; udiag via wave reduce ----
        {
            const float atot = sA[63*LD + jl];
            #pragma unroll
            for (int i = 0; i < 16; ++i) {
                const int t = q + 4*i;                     // wave q handles t ≡ q (mod 4)
                const size_t gi = base + (size_t)(t0+t)*E_ + jl;
                const float rv = rb[gi], kv = kb[gi], vv = vb[gi];
                const float a = sA[t*LD + jl];
                const float aprev = (t > 0) ? sA[(t-1)*LD + jl] : 0.f;  // A - w
                sRD[t*LD+jl] = rv * expf(aprev);
                sKA[t*LD+jl] = kv * expf(atot - a);
                sV [t*LD+jl] = vv;
                float p = rv * u_reg * kv;
                #pragma unroll
                for (int off = 32; off > 0; off >>= 1) p += __shfl_down(p, off);
                if (jl == 0) sUD[t] = p;
            }
        }
        __syncthreads();
        // ---- B1: Q = RD·KAᵀ·exp(-Atot) -> sPQ ----
        {
            float qacc[4][4] = {};
            for (int j = 0; j < 64; ++j) {
                const float ea = expf(-sA[63*LD + j]);
                float av[4], bv[4];
                #pragma unroll
                for (int i = 0; i < 4; ++i) av[i] = sRD[(ty*4+i)*LD + j];
                #pragma unroll
                for (int c = 0; c < 4; ++c) bv[c] = sKA[(tx*4+c)*LD + j] * ea;
                #pragma unroll
                for (int i = 0; i < 4; ++i)
                    #pragma unroll
                    for (int c = 0; c < 4; ++c) qacc[i][c] += av[i]*bv[c];
            }
            #pragma unroll
            for (int i = 0; i < 4; ++i)
                #pragma unroll
                for (int c = 0; c < 4; ++c)
                    sPQ[(ty*4+i)*LD + tx*4+c] = qacc[i][c];
        }
        __syncthreads();
        // ---- B2: yacc = tril(Q,-1)@V + udiag·v ----
        float yacc[4][4] = {};
        {
            for (int s = 0; s < 64; ++s) {
                float bv[4];
                #pragma unroll
                for (int c = 0; c < 4; ++c) bv[c] = sV[s*LD + tx*4+c];
                #pragma unroll
                for (int i = 0; i < 4; ++i) {
                    const int t = ty*4+i;
                    float qv = (s < t) ? sPQ[t*LD + s] : 0.f;
                    #pragma unroll
                    for (int c = 0; c < 4; ++c) yacc[i][c] += qv * bv[c];
                }
            }
            #pragma unroll
            for (int i = 0; i < 4; ++i) {
                const int t = ty*4+i;
                const float ud = sUD[t];
                #pragma unroll
                for (int c = 0; c < 4; ++c) yacc[i][c] += ud * sV[t*LD + tx*4+c];
            }
        }
        __syncthreads();
        // ---- C: Bcum = cumsum_t(A) per column; sA <- BF, sV <- VX, sB63 ----
        {
            float av[16], loc[16]; float cum = 0.f;
            #pragma unroll
            for (int c = 0; c < 16; ++c) {
                av[c] = sA[(q*16+c)*LD + jl];
                cum += av[c]; loc[c] = cum;
            }
            sQS[q][jl] = cum;
            __syncthreads();
            float pre = 0.f;
            for (int qq = 0; qq < q; ++qq) pre += sQS[qq][jl];
            #pragma unroll
            for (int c = 0; c < 16; ++c) {
                const float Bv = loc[c] + pre;
                const int t = q*16 + c;
                sA[t*LD + jl] = expf(Bv - av[c]);   // BF = exp(Bcum[t-1])
                sV[t*LD + jl] *= expf(-Bv);          // VX
                if (t == 63) sB63[jl] = expf(Bv);
            }
        }
        __syncthreads();
        // ---- D1: P = RD·KAᵀ -> sPQ ----
        {
            float pacc[4][4] = {};
            for (int j = 0; j < 64; ++j) {
                float av[4], bv[4];
                #pragma unroll
                for (int i = 0; i < 4; ++i) av[i] = sRD[(ty*4+i)*LD + j];
                #pragma unroll
                for (int c = 0; c < 4; ++c) bv[c] = sKA[(tx*4+c)*LD + j];
                #pragma unroll
                for (int i = 0; i < 4; ++i)
                    #pragma unroll
                    for (int c = 0; c < 4; ++c) pacc[i][c] += av[i]*bv[c];
            }
            #pragma unroll
            for (int i = 0; i < 4; ++i)
                #pragma unroll
                for (int c = 0; c < 4; ++c)
                    sPQ[(ty*4+i)*LD + tx*4+c] = pacc[i][c];
        }
        __syncthreads();
        // ---- D2: inter = BF·(RD@S0 + tril(P,-1)@VX); write y ----
        {
            float y1[4][4] = {};
            for (int j = 0; j < 64; ++j) {
                float av[4], sv[4];
                #pragma unroll
                for (int i = 0; i < 4; ++i) av[i] = sRD[(ty*4+i)*LD + j];
                #pragma unroll
                for (int c = 0; c < 4; ++c) sv[c] = sS0[j*LD + tx*4+c];
                #pragma unroll
                for (int i = 0; i < 4; ++i)
                    #pragma unroll
                    for (int c = 0; c < 4; ++c) y1[i][c] += av[i]*sv[c];
            }
            for (int s = 0; s < 64; ++s) {
                float vv[4];
                #pragma unroll
                for (int c = 0; c < 4; ++c) vv[c] = sV[s*LD + tx*4+c];
                #pragma unroll
                for (int i = 0; i < 4; ++i) {
                    const int t = ty*4+i;
                    float pv = (s < t) ? sPQ[t*LD + s] : 0.f;
                    #pragma unroll
                    for (int c = 0; c < 4; ++c) y1[i][c] += pv*vv[c];
                }
            }
            #pragma unroll
            for (int i = 0; i < 4; ++i) {
                const int t = ty*4+i;
                #pragma unroll
                for (int c = 0; c < 4; ++c) {
                    const int k = tx*4+c;
                    float val = yacc[i][c] + sA[t*LD + k] * y1[i][c];
                    yb[base + (size_t)(t0+t)*E_ + k] = val;
                }
            }
        }
        __syncthreads();
        // ---- E: S0 = exp(B63[k])·(S0 + KAᵀ@VX) ----
        {
            float sacc[4][4] = {};
            for (int s = 0; s < 64; ++s) {
                float kv[4], vv[4];
                #pragma unroll
                for (int i = 0; i < 4; ++i) kv[i] = sKA[s*LD + ty*4+i];
                #pragma unroll
                for (int c = 0; c < 4; ++c) vv[c] = sV[s*LD + tx*4+c];
                #pragma unroll
                for (int i = 0; i < 4; ++i)
                    #pragma unroll
                    for (int c = 0; c < 4; ++c) sacc[i][c] += kv[i]*vv[c];
            }
            #pragma unroll
            for (int i = 0; i < 4; ++i) {
                #pragma unroll
                for (int c = 0; c < 4; ++c) {
                    const int j = ty*4+i, k = tx*4+c;
                    const int idx = j*LD + k;
                    sS0[idx] = sB63[k] * (sS0[idx] + sacc[i][c]);
                }
            }
        }
        __syncthreads();
    }
    for (int i = tid; i < 4096; i += 256)
        st_out[(size_t)lane*4096 + i] = sS0[(i>>6)*LD + (i&63)];
}

// ---------------- GroupNorm (global stats per head) ----------------
__global__ __launch_bounds__(256) void gn_stats_k(const float* __restrict__ y,
        float* __restrict__ part)
{
    const int h = blockIdx.x, slab = blockIdx.y;   // 16 x 32
    const int tid = threadIdx.x;
    float s = 0.f, ss = 0.f;
    for (int i = tid; i < 2048; i += 256) {        // 32 rows x 64 cols
        int r = slab*32 + (i >> 6), k = i & 63;
        float v = y[(size_t)r*E_ + h*64 + k];
        s += v; ss += v*v;
    }
    #pragma unroll
    for (int off = 32; off > 0; off >>= 1) {
        s  += __shfl_down(s, off);
        ss += __shfl_down(ss, off);
    }
    __shared__ float ps[4], pss[4];
    if ((tid & 63) == 0) { ps[tid>>6] = s; pss[tid>>6] = ss; }
    __syncthreads();
    if (tid == 0) {
        part[h*32 + slab]       = ps[0]+ps[1]+ps[2]+ps[3];
        part[512 + h*32 + slab] = pss[0]+pss[1]+pss[2]+pss[3];
    }
}

__global__ __launch_bounds__(256) void gn_reduce_k(const float* __restrict__ part,
        float* __restrict__ stats)
{
    int tid = threadIdx.x;
    if (tid < 16) {
        float s = 0.f, ss = 0.f;
        for (int sl = 0; sl < 32; ++sl) {
            s  += part[tid*32 + sl];
            ss += part[512 + tid*32 + sl];
        }
        float mu  = s * (1.f/65536.f);
        float var = ss * (1.f/65536.f) - mu*mu;
        stats[tid]      = mu;
        stats[16 + tid] = rsqrtf(var + 1e-5f);
    }
}

__global__ __launch_bounds__(256) void gn_apply_k(const float* __restrict__ y,
        const float* __restrict__ g, const float* __restrict__ stats,
        const float* __restrict__ sc, const float* __restrict__ bi,
        float* __restrict__ z)
{
    int idx = blockIdx.x*256 + threadIdx.x;
    int d = idx & 1023;
    int h = d >> 6;
    float mu = stats[h], rstd = stats[16 + h];
    float yn = (y[idx] - mu)*rstd*sc[d] + bi[d];
    z[idx] = yn * g[idx];
}

// ---------------- launch ----------------
extern "C" void kernel_launch(void* const* d_in, const int* in_sizes, int n_in,
                              void* d_out, int out_size, void* d_ws, size_t ws_size,
                              hipStream_t stream)
{
    const float* x       = (const float*)d_in[0];
    const float* state0  = (const float*)d_in[1];
    const float* maa_x   = (const float*)d_in[2];
    const float* maa_w   = (const float*)d_in[3];
    const float* maa_k   = (const float*)d_in[4];
    const float* maa_v   = (const float*)d_in[5];
    const float* maa_r   = (const float*)d_in[6];
    const float* maa_g   = (const float*)d_in[7];
    const float* tdecay  = (const float*)d_in[8];
    const float* faaaa   = (const float*)d_in[9];
    const float* w1      = (const float*)d_in[10];
    const float* w2      = (const float*)d_in[11];
    const float* dw1     = (const float*)d_in[12];
    const float* dw2     = (const float*)d_in[13];
    const float* Wr      = (const float*)d_in[14];
    const float* Wk      = (const float*)d_in[15];
    const float* Wv      = (const float*)d_in[16];
    const float* Wg      = (const float*)d_in[17];
    const float* Wo      = (const float*)d_in[18];
    const float* lnx_s   = (const float*)d_in[19];
    const float* lnx_b   = (const float*)d_in[20];
    const float* maa_kch = (const float*)d_in[21];
    const float* maa_rch = (const float*)d_in[22];
    const float* Wk_ch   = (const float*)d_in[23];
    const float* Wv_ch   = (const float*)d_in[24];
    const float* Wr_ch   = (const float*)d_in[25];
    const float* ln1_s   = (const float*)d_in[26];
    const float* ln1_b   = (const float*)d_in[27];
    const float* ln2_s   = (const float*)d_in[28];
    const float* ln2_b   = (const float*)d_in[29];

    float* ws = (float*)d_ws;
    float* xn    = ws;                                     // A
    float* xmix  = ws + 1*(size_t)BTE;                     // B  (-> r, -> ar)
    float* t5    = ws + 2*(size_t)BTE;                     // 163840
    float* hdec  = ws + 2*(size_t)BTE + 163840;            // 65536
    float* gnpart= ws + 2*(size_t)BTE + 163840 + 65536;    // 1024
    float* gnstat= gnpart + 1024;                          // 32
    float* xw    = ws + 3*(size_t)BTE;                     // D0 (-> wlog)
    float* xk    = ws + 4*(size_t)BTE;                     // D1 (-> y)
    float* xvb   = ws + 5*(size_t)BTE;                     // D2 (-> z)
    float* xr    = ws + 6*(size_t)BTE;                     // D3 (-> x2)
    float* xg    = ws + 7*(size_t)BTE;                     // D4 (-> xn2)
    float* vbuf  = ws + 8*(size_t)BTE;                     // G  (-> kvb)
    float* gbuf  = ws + 9*(size_t)BTE;                     // H
    float* kkbuf = ws + 10*(size_t)BTE;                    // 4*BTE
    // aliases (ordered reuse; see liveness in launch order)
    float* rbuf   = xmix;
    float* kbuf   = xn;
    float* wlogb  = xw;
    float* ybuf   = xk;
    float* zbuf   = xvb;
    float* x2buf  = xr;
    float* xn2buf = xg;
    float* akbuf  = xn;
    float* arbuf  = xmix;
    float* kvbbuf = vbuf;

    float* out  = (float*)d_out;
    float* stout = out + (size_t)BTE;

    // ---- time mixing ----
    ln_rows_k<<<1024, 256, 0, stream>>>(x, ln1_s, ln1_b, xn);
    mix_x_k<<<4096, 256, 0, stream>>>(xn, maa_x, xmix);
    gemm_k<EPI_TANH><<<dim3(3,16), 256, 0, stream>>>(xmix, w1, t5, 1024, 160, 1024, nullptr, nullptr);
    mix5_k<<<1024, 256, 0, stream>>>(xn, t5, w2, maa_w, maa_k, maa_v, maa_r, maa_g,
                                     xw, xk, xvb, xr, xg);
    gemm_k<EPI_NONE><<<dim3(16,16), 256, 0, stream>>>(xr,  Wr, rbuf, 1024, 1024, 1024, nullptr, nullptr);
    gemm_k<EPI_NONE><<<dim3(16,16), 256, 0, stream>>>(xk,  Wk, kbuf, 1024, 1024, 1024, nullptr, nullptr);
    gemm_k<EPI_NONE><<<dim3(16,16), 256, 0, stream>>>(xvb, Wv, vbuf, 1024, 1024, 1024, nullptr, nullptr);
    gemm_k<EPI_SILU><<<dim3(16,16), 256, 0, stream>>>(xg,  Wg, gbuf, 1024, 1024, 1024, nullptr, nullptr);
    gemm_k<EPI_TANH><<<dim3(1,16),  256, 0, stream>>>(xw, dw1, hdec, 1024, 64, 1024, nullptr, nullptr);
    gemm_k<EPI_WLOG><<<dim3(16,16), 256, 0, stream>>>(hdec, dw2, wlogb, 1024, 1024, 64, tdecay, nullptr);
    chunkwise_k<<<32, 256, 0, stream>>>(rbuf, kbuf, vbuf, wlogb, faaaa, state0, ybuf, stout);
    gn_stats_k<<<dim3(16,32), 256, 0, stream>>>(ybuf, gnpart);
    gn_reduce_k<<<1, 256, 0, stream>>>(gnpart, gnstat);
    gn_apply_k<<<4096, 256, 0, stream>>>(ybuf, gbuf, gnstat, lnx_s, lnx_b, zbuf);
    gemm_k<EPI_ADDRES><<<dim3(16,16), 256, 0, stream>>>(zbuf, Wo, x2buf, 1024, 1024, 1024, x, nullptr);

    // ---- channel mixing ----
    ln_rows_k<<<1024, 256, 0, stream>>>(x2buf, ln2_s, ln2_b, xn2buf);
    mix_ch_k<<<4096, 256, 0, stream>>>(xn2buf, maa_kch, maa_rch, akbuf, arbuf);
    gemm_k<EPI_RELU2><<<dim3(64,16), 256, 0, stream>>>(akbuf, Wk_ch, kkbuf, 1024, 4096, 1024, nullptr, nullptr);
    gemm_k<EPI_NONE><<<dim3(16,16),  256, 0, stream>>>(kkbuf, Wv_ch, kvbbuf, 1024, 1024, 4096, nullptr, nullptr);
    gemm_k<EPI_SIGMUL><<<dim3(16,16),256, 0, stream>>>(arbuf, Wr_ch, out, 1024, 1024, 1024, kvbbuf, x2buf);
}

// Round 2
// 609.602 us; speedup vs baseline: 3.5256x; 3.5256x over previous
//
#include <hip/hip_runtime.h>
#include <math.h>

// RWKV block forward, MI355X — round 1: bf16 MFMA GEMMs + fused epilogues.
// B=2 T=512 E=1024 H=16 Sh=64 D=1024 F=4096 CHUNK=64
#define T_  512
#define E_  1024
#define BTE 1048576   // B*T*E elements

enum { EPI_NONE=0, EPI_TANH=1, EPI_SILU=2, EPI_RELU2=3, EPI_WLOG=4, EPI_ADDRES=5, EPI_SIGMUL=6 };

typedef __attribute__((ext_vector_type(8))) short bf16x8;
typedef __attribute__((ext_vector_type(4))) float f32x4;

__device__ __forceinline__ unsigned short f2bf(float f) {
    union { float f; unsigned u; } v; v.f = f;
    unsigned r = v.u + 0x7fffu + ((v.u >> 16) & 1u);
    return (unsigned short)(r >> 16);
}
__device__ __forceinline__ float bf2f(unsigned short h) {
    union { unsigned u; float f; } v; v.u = ((unsigned)h) << 16;
    return v.f;
}

// ---------------- LayerNorm over rows of length 1024 (fp32 out) ----------------
__global__ __launch_bounds__(256) void ln_rows_k(const float* __restrict__ x,
        const float* __restrict__ sc, const float* __restrict__ bi,
        float* __restrict__ out)
{
    const int row = blockIdx.x;
    const int tid = threadIdx.x;
    const float* xr = x + (size_t)row * E_;
    float4 v = *reinterpret_cast<const float4*>(xr + tid*4);
    float s  = v.x + v.y + v.z + v.w;
    float ss = v.x*v.x + v.y*v.y + v.z*v.z + v.w*v.w;
    #pragma unroll
    for (int off = 32; off > 0; off >>= 1) {
        s  += __shfl_down(s, off);
        ss += __shfl_down(ss, off);
    }
    __shared__ float ps[4], pss[4];
    __shared__ float smu, srstd;
    if ((tid & 63) == 0) { ps[tid>>6] = s; pss[tid>>6] = ss; }
    __syncthreads();
    if (tid == 0) {
        float S  = ps[0]+ps[1]+ps[2]+ps[3];
        float SS = pss[0]+pss[1]+pss[2]+pss[3];
        float mu  = S * (1.f/E_);
        float var = SS * (1.f/E_) - mu*mu;
        smu = mu; srstd = rsqrtf(var + 1e-5f);
    }
    __syncthreads();
    const float mu = smu, rstd = srstd;
    float4 s4 = *reinterpret_cast<const float4*>(sc + tid*4);
    float4 b4 = *reinterpret_cast<const float4*>(bi + tid*4);
    float4 o;
    o.x = (v.x-mu)*rstd*s4.x + b4.x;
    o.y = (v.y-mu)*rstd*s4.y + b4.y;
    o.z = (v.z-mu)*rstd*s4.z + b4.z;
    o.w = (v.w-mu)*rstd*s4.w + b4.w;
    *reinterpret_cast<float4*>(out + (size_t)row*E_ + tid*4) = o;
}

// ---------------- xmix = xn + (shift(xn)-xn)*maa_x  (bf16 out) ----------------
__global__ __launch_bounds__(256) void mix_x_k(const float* __restrict__ xn,
        const float* __restrict__ maa, unsigned short* __restrict__ out)
{
    int idx = blockIdx.x*256 + threadIdx.x;     // < BTE
    int e = idx & 1023;
    int t = (idx >> 10) & 511;
    float xv = xn[idx];
    float prev = t ? xn[idx - E_] : 0.f;
    out[idx] = f2bf(xv + (prev - xv) * maa[e]);
}

// ---------------- channel-mix shift: ak/ar (bf16 out) ----------------
__global__ __launch_bounds__(256) void mix_ch_k(const float* __restrict__ xn2,
        const float* __restrict__ maaK, const float* __restrict__ maaR,
        unsigned short* __restrict__ ak, unsigned short* __restrict__ ar)
{
    int idx = blockIdx.x*256 + threadIdx.x;
    int e = idx & 1023;
    int t = (idx >> 10) & 511;
    float xv = xn2[idx];
    float prev = t ? xn2[idx - E_] : 0.f;
    float sxv = prev - xv;
    ak[idx] = f2bf(xv + sxv * maaK[e]);
    ar[idx] = f2bf(xv + sxv * maaR[e]);
}

// ---------------- mix5: xw/xk/xv/xr/xg from t5 @ W2 (reshape quirk), bf16 out ----------------
__global__ __launch_bounds__(256) void mix5_k(const float* __restrict__ xn,
        const float* __restrict__ t5, const float* __restrict__ W2,
        const float* __restrict__ maaW, const float* __restrict__ maaK,
        const float* __restrict__ maaV, const float* __restrict__ maaR,
        const float* __restrict__ maaG,
        unsigned short* __restrict__ xw, unsigned short* __restrict__ xk,
        unsigned short* __restrict__ xv, unsigned short* __restrict__ xr,
        unsigned short* __restrict__ xg)
{
    const int bt = blockIdx.x;
    const int b = bt >> 9, t = bt & 511;
    __shared__ float st5[5][32];
    __shared__ int sgs[5];
    const int tid = threadIdx.x;
    if (tid < 160) {
        int o = tid >> 5, c = tid & 31;
        int L = o*2 + b;
        int bs = L / 5, gs = L - bs*5;
        st5[o][c] = t5[((size_t)(bs*T_ + t))*160 + gs*32 + c];
        if (c == 0) sgs[o] = gs;
    }
    __syncthreads();
    const float* xnrow = xn + (size_t)bt*E_;
    const int g0=sgs[0], g1=sgs[1], g2=sgs[2], g3=sgs[3], g4=sgs[4];
    for (int e = tid; e < E_; e += 256) {
        float xnv = xnrow[e];
        float prev = (t > 0) ? xnrow[e - E_] : 0.f;
        float sxv = prev - xnv;
        float m0=0.f, m1=0.f, m2=0.f, m3=0.f, m4=0.f;
        #pragma unroll 4
        for (int c = 0; c < 32; ++c) {
            float a0 = st5[0][c], a1 = st5[1][c], a2 = st5[2][c], a3 = st5[3][c], a4 = st5[4][c];
            m0 += a0 * W2[((size_t)g0*32 + c)*E_ + e];
            m1 += a1 * W2[((size_t)g1*32 + c)*E_ + e];
            m2 += a2 * W2[((size_t)g2*32 + c)*E_ + e];
            m3 += a3 * W2[((size_t)g3*32 + c)*E_ + e];
            m4 += a4 * W2[((size_t)g4*32 + c)*E_ + e];
        }
        size_t oidx = (size_t)bt*E_ + e;
        xw[oidx] = f2bf(xnv + sxv*(maaW[e] + m0));
        xk[oidx] = f2bf(xnv + sxv*(maaK[e] + m1));
        xv[oidx] = f2bf(xnv + sxv*(maaV[e] + m2));
        xr[oidx] = f2bf(xnv + sxv*(maaR[e] + m3));
        xg[oidx] = f2bf(xnv + sxv*(maaG[e] + m4));
    }
}

// ---------------- weight convert+transpose: dst[n][k] = bf16(src[k][n]) ----------------
struct TransArgs {
    const float* src[6];
    unsigned short* dst[6];
    int K, N, Npad;
};
__global__ __launch_bounds__(256) void wtrans_k(TransArgs a)
{
    const int z = blockIdx.z;
    const float* S = a.src[z];
    unsigned short* D = a.dst[z];
    __shared__ float t[64][65];
    const int tid = threadIdx.x;
    const int k0 = blockIdx.y*64, n0 = blockIdx.x*64;
    #pragma unroll
    for (int i = 0; i < 16; ++i) {
        int r = i*4 + (tid >> 6), c = tid & 63;
        int gk = k0 + r, gn = n0 + c;
        t[r][c] = (gk < a.K && gn < a.N) ? S[(size_t)gk*a.N + gn] : 0.f;
    }
    __syncthreads();
    #pragma unroll
    for (int i = 0; i < 16; ++i) {
        int r = i*4 + (tid >> 6), c = tid & 63;
        int gn = n0 + r, gk = k0 + c;
        if (gn < a.Npad && gk < a.K)
            D[(size_t)gn*a.K + gk] = f2bf(t[c][r]);
    }
}

// ---------------- bf16 MFMA GEMM: C = epi(A(MxK) @ B), B given transposed (Npad x K) ----------------
// 64x64 tile, BK=64, 4 waves, wave computes 32x32 via 2x2 of 16x16x32 MFMA.
// LDS staged via global_load_lds(16B) with XOR swizzle (byte ^= (row&7)<<4) applied
// on the GLOBAL source; reads apply the same swizzle (both-sides, rule #21).
struct GemmArgs {
    const unsigned short* A[4];
    const unsigned short* B[4];
    void* C[4];
    const float* p1[4];
    const float* p2[4];
    int epi[4];
    int obf[4];
    int M, N, K;
};
__global__ __launch_bounds__(256) void mgemm_k(GemmArgs g)
{
    const int bz = blockIdx.z;
    const unsigned short* Aг = g.A[bz];
    const unsigned short* BT = g.B[bz];
    const int N = g.N, K = g.K;
    const int m0 = blockIdx.y * 64, n0 = blockIdx.x * 64;
    const int tid = threadIdx.x;
    const int lane = tid & 63, w = tid >> 6;

    __shared__ __align__(16) unsigned short As[2][4096];
    __shared__ __align__(16) unsigned short Bs[2][4096];

    // staging plan: wave w issues instrs t = 4w..4w+3 (t<8 -> A-tile, else B-tile)
    const size_t rowBytes = (size_t)K * 2;
    int sI[4], sIsB[4]; size_t sOff[4];
    #pragma unroll
    for (int ii = 0; ii < 4; ++ii) {
        int t = w*4 + ii;
        int isB = t >> 3;
        int i = t & 7;
        int r = i*8 + (lane >> 3);
        int gb = ((lane & 7) * 16) ^ ((r & 7) << 4);   // inverse-swizzled source column
        sI[ii] = i; sIsB[ii] = isB;
        int srow = (isB ? n0 : m0) + r;
        sOff[ii] = (size_t)srow * rowBytes + gb;
    }
    auto stage = [&](int buf, int k0) {
        const char* Abase = (const char*)Aг + (size_t)k0 * 2;
        const char* Bbase = (const char*)BT + (size_t)k0 * 2;
        #pragma unroll
        for (int ii = 0; ii < 4; ++ii) {
            const char* src = (sIsB[ii] ? Bbase : Abase) + sOff[ii];
            unsigned short* dst = (sIsB[ii] ? Bs[buf] : As[buf]) + sI[ii]*512;
            auto g1 = (const __attribute__((address_space(1))) unsigned int*)(src);
            auto l3 = (__attribute__((address_space(3))) unsigned int*)(uintptr_t)(dst);
            __builtin_amdgcn_global_load_lds(g1, l3, 16, 0, 0);
        }
    };

    // fragment read offsets (bytes), swizzled
    const int wm = (w >> 1) * 32, wn = (w & 1) * 32;
    const int lr = lane & 15, lk = lane >> 4;
    int aoff[2][2], boff[2][2];
    #pragma unroll
    for (int mi = 0; mi < 2; ++mi)
        #pragma unroll
        for (int kw = 0; kw < 2; ++kw) {
            int ar = wm + mi*16 + lr;
            aoff[mi][kw] = ar*128 + ((kw*64 + lk*16) ^ ((ar & 7) << 4));
            int br = wn + mi*16 + lr;
            boff[mi][kw] = br*128 + ((kw*64 + lk*16) ^ ((br & 7) << 4));
        }

    f32x4 acc[2][2] = {};
    stage(0, 0);
    const int nk = K >> 6;
    int cur = 0;
    for (int kt = 0; kt < nk; ++kt) {
        __syncthreads();                       // drains vmcnt: buf `cur` staged; prev compute done
        if (kt + 1 < nk) stage(cur ^ 1, (kt + 1) << 6);
        const char* Ab = (const char*)As[cur];
        const char* Bb = (const char*)Bs[cur];
        bf16x8 af[2][2], bfv[2][2];
        #pragma unroll
        for (int mi = 0; mi < 2; ++mi)
            #pragma unroll
            for (int kw = 0; kw < 2; ++kw) {
                af[mi][kw]  = *(const bf16x8*)(Ab + aoff[mi][kw]);
                bfv[mi][kw] = *(const bf16x8*)(Bb + boff[mi][kw]);
            }
        #pragma unroll
        for (int kw = 0; kw < 2; ++kw)
            #pragma unroll
            for (int mi = 0; mi < 2; ++mi)
                #pragma unroll
                for (int ni = 0; ni < 2; ++ni)
                    acc[mi][ni] = __builtin_amdgcn_mfma_f32_16x16x32_bf16(
                        af[mi][kw], bfv[ni][kw], acc[mi][ni], 0, 0, 0);
        cur ^= 1;
    }

    // epilogue (runtime-uniform per block)
    const int epi = g.epi[bz], obf = g.obf[bz];
    const float* p1 = g.p1[bz];
    const float* p2 = g.p2[bz];
    float* Cf = (float*)g.C[bz];
    unsigned short* Ch = (unsigned short*)g.C[bz];
    #pragma unroll
    for (int mi = 0; mi < 2; ++mi) {
        #pragma unroll
        for (int ni = 0; ni < 2; ++ni) {
            #pragma unroll
            for (int j = 0; j < 4; ++j) {
                int gm = m0 + wm + mi*16 + lk*4 + j;      // C/D: row=(lane>>4)*4+reg
                int gn = n0 + wn + ni*16 + lr;            //      col=lane&15
                if (gn >= N) continue;
                size_t idx = (size_t)gm * N + gn;
                float a = acc[mi][ni][j];
                float o = a;
                if (epi == EPI_TANH)        o = tanhf(a);
                else if (epi == EPI_SILU)   o = a / (1.f + expf(-a));
                else if (epi == EPI_RELU2)  { float r = fmaxf(a, 0.f); o = r*r; }
                else if (epi == EPI_WLOG) {
                    float z = -(p1[gn] + a);
                    float sp = (z > 15.f) ? z : log1pf(expf(z));
                    o = logf(fminf(fmaxf(sp, 1e-6f), 1.f));
                }
                else if (epi == EPI_ADDRES) o = a + p1[idx];
                else if (epi == EPI_SIGMUL) o = p2[idx] + p1[idx] / (1.f + expf(-a));
                if (obf) Ch[idx] = f2bf(o); else Cf[idx] = o;
            }
        }
    }
}

// ---------------- chunkwise RWKV scan (bf16 r/k/v inputs, fp32 math) ----------------
__global__ __launch_bounds__(256) void chunkwise_k(
    const unsigned short* __restrict__ rb, const unsigned short* __restrict__ kb,
    const unsigned short* __restrict__ vb, const float* __restrict__ wb,
    const float* __restrict__ faaaa, const float* __restrict__ st_in,
    float* __restrict__ yb, float* __restrict__ st_out)
{
    const int lane = blockIdx.x;          // b*16 + h
    const int b = lane >> 4, h = lane & 15;
    const int tid = threadIdx.x;
    const int LD = 65;

    __shared__ float sS0[64*65];
    __shared__ float sRD[64*65];
    __shared__ float sKA[64*65];
    __shared__ float sV [64*65];
    __shared__ float sA [64*65];
    __shared__ float sPQ[64*65];
    __shared__ float sUD[64];
    __shared__ float sB63[64];
    __shared__ float sQS[4][64];

    for (int i = tid; i < 4096; i += 256)
        sS0[(i>>6)*LD + (i&63)] = st_in[(size_t)lane*4096 + i];

    const int jl = tid & 63;
    const int q  = tid >> 6;
    const float u_reg = faaaa[h*64 + jl];
    const size_t base = (size_t)b*T_*E_ + (size_t)h*64;
    const int tx = tid & 15, ty = tid >> 4;
    __syncthreads();

    for (int nc = 0; nc < 8; ++nc) {
        const int t0 = nc*64;
        // A1: cumsum(wlog) over t within chunk -> sA
        {
            float loc[16]; float cum = 0.f;
            #pragma unroll
            for (int c = 0; c < 16; ++c) {
                float wv = wb[base + (size_t)(t0 + q*16 + c)*E_ + jl];
                cum += wv; loc[c] = cum;
            }
            sQS[q][jl] = cum;
            __syncthreads();
            float pre = 0.f;
            for (int qq = 0; qq < q; ++qq) pre += sQS[qq][jl];
            #pragma unroll
            for (int c = 0; c < 16; ++c) sA[(q*16+c)*LD + jl] = loc[c] + pre;
        }
        __syncthreads();
        // A2: load r,k,v; RD/KA transforms; udiag via wave reduce
        {
            const float atot = sA[63*LD + jl];
            #pragma unroll
            for (int i = 0; i < 16; ++i) {
                const int t = q + 4*i;
                const size_t gi = base + (size_t)(t0+t)*E_ + jl;
                const float rv = bf2f(rb[gi]), kv = bf2f(kb[gi]), vv = bf2f(vb[gi]);
                const float a = sA[t*LD + jl];
                const float aprev = (t > 0) ? sA[(t-1)*LD + jl] : 0.f;
                sRD[t*LD+jl] = rv * expf(aprev);
                sKA[t*LD+jl] = kv * expf(atot - a);
                sV [t*LD+jl] = vv;
                float p = rv * u_reg * kv;
                #pragma unroll
                for (int off = 32; off > 0; off >>= 1) p += __shfl_down(p, off);
                if (jl == 0) sUD[t] = p;
            }
        }
        __syncthreads();
        // B1: Q = RD·KAᵀ·exp(-Atot) -> sPQ
        {
            float qacc[4][4] = {};
            for (int j = 0; j < 64; ++j) {
                const float ea = expf(-sA[63*LD + j]);
                float av[4], bv[4];
                #pragma unroll
                for (int i = 0; i < 4; ++i) av[i] = sRD[(ty*4+i)*LD + j];
                #pragma unroll
                for (int c = 0; c < 4; ++c) bv[c] = sKA[(tx*4+c)*LD + j] * ea;
                #pragma unroll
                for (int i = 0; i < 4; ++i)
                    #pragma unroll
                    for (int c = 0; c < 4; ++c) qacc[i][c] += av[i]*bv[c];
            }
            #pragma unroll
            for (int i = 0; i < 4; ++i)
                #pragma unroll
                for (int c = 0; c < 4; ++c)
                    sPQ[(ty*4+i)*LD + tx*4+c] = qacc[i][c];
        }
        __syncthreads();
        // B2: yacc = tril(Q,-1)@V + udiag·v
        float yacc[4][4] = {};
        {
            for (int s = 0; s < 64; ++s) {
                float bv[4];
                #pragma unroll
                for (int c = 0; c < 4; ++c) bv[c] = sV[s*LD + tx*4+c];
                #pragma unroll
                for (int i = 0; i < 4; ++i) {
                    const int t = ty*4+i;
                    float qv = (s < t) ? sPQ[t*LD + s] : 0.f;
                    #pragma unroll
                    for (int c = 0; c < 4; ++c) yacc[i][c] += qv * bv[c];
                }
            }
            #pragma unroll
            for (int i = 0; i < 4; ++i) {
                const int t = ty*4+i;
                const float ud = sUD[t];
                #pragma unroll
                for (int c = 0; c < 4; ++c) yacc[i][c] += ud * sV[t*LD + tx*4+c];
            }
        }
        __syncthreads();
        // C: Bcum = cumsum_t(A) per column; sA <- BF, sV <- VX, sB63
        {
            float av[16], loc[16]; float cum = 0.f;
            #pragma unroll
            for (int c = 0; c < 16; ++c) {
                av[c] = sA[(q*16+c)*LD + jl];
                cum += av[c]; loc[c] = cum;
            }
            sQS[q][jl] = cum;
            __syncthreads();
            float pre = 0.f;
            for (int qq = 0; qq < q; ++qq) pre += sQS[qq][jl];
            #pragma unroll
            for (int c = 0; c < 16; ++c) {
                const float Bv = loc[c] + pre;
                const int t = q*16 + c;
                sA[t*LD + jl] = expf(Bv - av[c]);
                sV[t*LD + jl] *= expf(-Bv);
                if (t == 63) sB63[jl] = expf(Bv);
            }
        }
        __syncthreads();
        // D1: P = RD·KAᵀ -> sPQ
        {
            float pacc[4][4] = {};
            for (int j = 0; j < 64; ++j) {
                float av[4], bv[4];
                #pragma unroll
                for (int i = 0; i < 4; ++i) av[i] = sRD[(ty*4+i)*LD + j];
                #pragma unroll
                for (int c = 0; c < 4; ++c) bv[c] = sKA[(tx*4+c)*LD + j];
                #pragma unroll
                for (int i = 0; i < 4; ++i)
                    #pragma unroll
                    for (int c = 0; c < 4; ++c) pacc[i][c] += av[i]*bv[c];
            }
            #pragma unroll
            for (int i = 0; i < 4; ++i)
                #pragma unroll
                for (int c = 0; c < 4; ++c)
                    sPQ[(ty*4+i)*LD + tx*4+c] = pacc[i][c];
        }
        __syncthreads();
        // D2: inter = BF·(RD@S0 + tril(P,-1)@VX); write y
        {
            float y1[4][4] = {};
            for (int j = 0; j < 64; ++j) {
                float av[4], sv[4];
                #pragma unroll
                for (int i = 0; i < 4; ++i) av[i] = sRD[(ty*4+i)*LD + j];
                #pragma unroll
                for (int c = 0; c < 4; ++c) sv[c] = sS0[j*LD + tx*4+c];
                #pragma unroll
                for (int i = 0; i < 4; ++i)
                    #pragma unroll
                    for (int c = 0; c < 4; ++c) y1[i][c] += av[i]*sv[c];
            }
            for (int s = 0; s < 64; ++s) {
                float vv[4];
                #pragma unroll
                for (int c = 0; c < 4; ++c) vv[c] = sV[s*LD + tx*4+c];
                #pragma unroll
                for (int i = 0; i < 4; ++i) {
                    const int t = ty*4+i;
                    float pv = (s < t) ? sPQ[t*LD + s] : 0.f;
                    #pragma unroll
                    for (int c = 0; c < 4; ++c) y1[i][c] += pv*vv[c];
                }
            }
            #pragma unroll
            for (int i = 0; i < 4; ++i) {
                const int t = ty*4+i;
                #pragma unroll
                for (int c = 0; c < 4; ++c) {
                    const int k = tx*4+c;
                    float val = yacc[i][c] + sA[t*LD + k] * y1[i][c];
                    yb[base + (size_t)(t0+t)*E_ + k] = val;
                }
            }
        }
        __syncthreads();
        // E: S0 = exp(B63[k])·(S0 + KAᵀ@VX)
        {
            float sacc[4][4] = {};
            for (int s = 0; s < 64; ++s) {
                float kv[4], vv[4];
                #pragma unroll
                for (int i = 0; i < 4; ++i) kv[i] = sKA[s*LD + ty*4+i];
                #pragma unroll
                for (int c = 0; c < 4; ++c) vv[c] = sV[s*LD + tx*4+c];
                #pragma unroll
                for (int i = 0; i < 4; ++i)
                    #pragma unroll
                    for (int c = 0; c < 4; ++c) sacc[i][c] += kv[i]*vv[c];
            }
            #pragma unroll
            for (int i = 0; i < 4; ++i) {
                #pragma unroll
                for (int c = 0; c < 4; ++c) {
                    const int j = ty*4+i, k = tx*4+c;
                    const int idx = j*LD + k;
                    sS0[idx] = sB63[k] * (sS0[idx] + sacc[i][c]);
                }
            }
        }
        __syncthreads();
    }
    for (int i = tid; i < 4096; i += 256)
        st_out[(size_t)lane*4096 + i] = sS0[(i>>6)*LD + (i&63)];
}

// ---------------- GroupNorm (global stats per head) ----------------
__global__ __launch_bounds__(256) void gn_stats_k(const float* __restrict__ y,
        float* __restrict__ part)
{
    const int h = blockIdx.x, slab = blockIdx.y;
    const int tid = threadIdx.x;
    float s = 0.f, ss = 0.f;
    for (int i = tid; i < 2048; i += 256) {
        int r = slab*32 + (i >> 6), k = i & 63;
        float v = y[(size_t)r*E_ + h*64 + k];
        s += v; ss += v*v;
    }
    #pragma unroll
    for (int off = 32; off > 0; off >>= 1) {
        s  += __shfl_down(s, off);
        ss += __shfl_down(ss, off);
    }
    __shared__ float ps[4], pss[4];
    if ((tid & 63) == 0) { ps[tid>>6] = s; pss[tid>>6] = ss; }
    __syncthreads();
    if (tid == 0) {
        part[h*32 + slab]       = ps[0]+ps[1]+ps[2]+ps[3];
        part[512 + h*32 + slab] = pss[0]+pss[1]+pss[2]+pss[3];
    }
}

__global__ __launch_bounds__(256) void gn_reduce_k(const float* __restrict__ part,
        float* __restrict__ stats)
{
    int tid = threadIdx.x;
    if (tid < 16) {
        float s = 0.f, ss = 0.f;
        for (int sl = 0; sl < 32; ++sl) {
            s  += part[tid*32 + sl];
            ss += part[512 + tid*32 + sl];
        }
        float mu  = s * (1.f/65536.f);
        float var = ss * (1.f/65536.f) - mu*mu;
        stats[tid]      = mu;
        stats[16 + tid] = rsqrtf(var + 1e-5f);
    }
}

__global__ __launch_bounds__(256) void gn_apply_k(const float* __restrict__ y,
        const float* __restrict__ g, const float* __restrict__ stats,
        const float* __restrict__ sc, const float* __restrict__ bi,
        unsigned short* __restrict__ z)
{
    int idx = blockIdx.x*256 + threadIdx.x;
    int d = idx & 1023;
    int h = d >> 6;
    float mu = stats[h], rstd = stats[16 + h];
    float yn = (y[idx] - mu)*rstd*sc[d] + bi[d];
    z[idx] = f2bf(yn * g[idx]);
}

// ---------------- launch ----------------
extern "C" void kernel_launch(void* const* d_in, const int* in_sizes, int n_in,
                              void* d_out, int out_size, void* d_ws, size_t ws_size,
                              hipStream_t stream)
{
    const float* x       = (const float*)d_in[0];
    const float* state0  = (const float*)d_in[1];
    const float* maa_x   = (const float*)d_in[2];
    const float* maa_w   = (const float*)d_in[3];
    const float* maa_k   = (const float*)d_in[4];
    const float* maa_v   = (const float*)d_in[5];
    const float* maa_r   = (const float*)d_in[6];
    const float* maa_g   = (const float*)d_in[7];
    const float* tdecay  = (const float*)d_in[8];
    const float* faaaa   = (const float*)d_in[9];
    const float* w1      = (const float*)d_in[10];
    const float* w2      = (const float*)d_in[11];
    const float* dw1     = (const float*)d_in[12];
    const float* dw2     = (const float*)d_in[13];
    const float* Wr      = (const float*)d_in[14];
    const float* Wk      = (const float*)d_in[15];
    const float* Wv      = (const float*)d_in[16];
    const float* Wg      = (const float*)d_in[17];
    const float* Wo      = (const float*)d_in[18];
    const float* lnx_s   = (const float*)d_in[19];
    const float* lnx_b   = (const float*)d_in[20];
    const float* maa_kch = (const float*)d_in[21];
    const float* maa_rch = (const float*)d_in[22];
    const float* Wk_ch   = (const float*)d_in[23];
    const float* Wv_ch   = (const float*)d_in[24];
    const float* Wr_ch   = (const float*)d_in[25];
    const float* ln1_s   = (const float*)d_in[26];
    const float* ln1_b   = (const float*)d_in[27];
    const float* ln2_s   = (const float*)d_in[28];
    const float* ln2_b   = (const float*)d_in[29];

    // ---- workspace layout ----
    float* xn     = (float*)d_ws;               // 1M f32 (reused as xn2)
    float* t5     = xn + 1048576;               // 163840
    float* gbuf   = t5 + 163840;                // 1M
    float* wlogb  = gbuf + 1048576;             // 1M
    float* ybuf   = wlogb + 1048576;            // 1M
    float* kvb    = ybuf + 1048576;             // 1M
    float* gnpart = kvb + 1048576;              // 1024
    float* gnstat = gnpart + 1024;              // 32
    unsigned short* u = (unsigned short*)(gnstat + 32);
    unsigned short* xmix = u;  u += 1048576;    // reused as z
    unsigned short* xw   = u;  u += 1048576;    // reused as ak
    unsigned short* xk   = u;  u += 1048576;    // reused as ar
    unsigned short* xv_  = u;  u += 1048576;    // kk[0:1M]
    unsigned short* xr   = u;  u += 1048576;    // kk[1M:2M]
    unsigned short* xg   = u;  u += 1048576;    // kk[2M:3M]
    /* kk extra 1M */          u += 1048576;    // kk[3M:4M]
    unsigned short* rb   = u;  u += 1048576;
    unsigned short* kb   = u;  u += 1048576;
    unsigned short* vb   = u;  u += 1048576;
    unsigned short* hdecb= u;  u += 65536;
    unsigned short* WrT  = u;  u += 1048576;
    unsigned short* WkT  = u;  u += 1048576;
    unsigned short* WvT  = u;  u += 1048576;
    unsigned short* WgT  = u;  u += 1048576;
    unsigned short* WoT  = u;  u += 1048576;
    unsigned short* WrchT= u;  u += 1048576;
    unsigned short* WkchT= u;  u += 4194304;    // 4096 x 1024
    unsigned short* WvchT= u;  u += 4194304;    // 1024 x 4096
    unsigned short* w1T  = u;  u += 196608;     // 192 x 1024 (zero-padded rows 160..191)
    unsigned short* dw1T = u;  u += 65536;      // 64 x 1024
    unsigned short* dw2T = u;  u += 65536;      // 1024 x 64
    unsigned short* zbuf = xmix;
    unsigned short* akb  = xw;
    unsigned short* arb  = xk;
    unsigned short* kkb  = xv_;                 // 4M contiguous

    float* out   = (float*)d_out;
    float* x2buf = out;                         // d_out reused as x2 scratch
    float* stout = out + (size_t)BTE;

    // ---- weight convert+transpose (once per launch) ----
    {
        TransArgs ta{}; ta.K = 1024; ta.N = 1024; ta.Npad = 1024;
        ta.src[0]=Wr; ta.src[1]=Wk; ta.src[2]=Wv; ta.src[3]=Wg; ta.src[4]=Wo; ta.src[5]=Wr_ch;
        ta.dst[0]=WrT; ta.dst[1]=WkT; ta.dst[2]=WvT; ta.dst[3]=WgT; ta.dst[4]=WoT; ta.dst[5]=WrchT;
        wtrans_k<<<dim3(16,16,6), 256, 0, stream>>>(ta);
    }
    { TransArgs ta{}; ta.K=1024; ta.N=4096; ta.Npad=4096; ta.src[0]=Wk_ch; ta.dst[0]=WkchT;
      wtrans_k<<<dim3(64,16,1), 256, 0, stream>>>(ta); }
    { TransArgs ta{}; ta.K=4096; ta.N=1024; ta.Npad=1024; ta.src[0]=Wv_ch; ta.dst[0]=WvchT;
      wtrans_k<<<dim3(16,64,1), 256, 0, stream>>>(ta); }
    { TransArgs ta{}; ta.K=1024; ta.N=160; ta.Npad=192; ta.src[0]=w1; ta.dst[0]=w1T;
      wtrans_k<<<dim3(3,16,1), 256, 0, stream>>>(ta); }
    { TransArgs ta{}; ta.K=1024; ta.N=64; ta.Npad=64; ta.src[0]=dw1; ta.dst[0]=dw1T;
      wtrans_k<<<dim3(1,16,1), 256, 0, stream>>>(ta); }
    { TransArgs ta{}; ta.K=64; ta.N=1024; ta.Npad=1024; ta.src[0]=dw2; ta.dst[0]=dw2T;
      wtrans_k<<<dim3(16,1,1), 256, 0, stream>>>(ta); }

    // ---- time mixing ----
    ln_rows_k<<<1024, 256, 0, stream>>>(x, ln1_s, ln1_b, xn);
    mix_x_k<<<4096, 256, 0, stream>>>(xn, maa_x, xmix);
    { GemmArgs g{}; g.M=1024; g.N=160; g.K=1024;
      g.A[0]=xmix; g.B[0]=w1T; g.C[0]=t5; g.epi[0]=EPI_TANH; g.obf[0]=0;
      mgemm_k<<<dim3(3,16,1), 256, 0, stream>>>(g); }
    mix5_k<<<1024, 256, 0, stream>>>(xn, t5, w2, maa_w, maa_k, maa_v, maa_r, maa_g,
                                     xw, xk, xv_, xr, xg);
    { GemmArgs g{}; g.M=1024; g.N=1024; g.K=1024;
      g.A[0]=xr;  g.B[0]=WrT; g.C[0]=rb;   g.epi[0]=EPI_NONE; g.obf[0]=1;
      g.A[1]=xk;  g.B[1]=WkT; g.C[1]=kb;   g.epi[1]=EPI_NONE; g.obf[1]=1;
      g.A[2]=xv_; g.B[2]=WvT; g.C[2]=vb;   g.epi[2]=EPI_NONE; g.obf[2]=1;
      g.A[3]=xg;  g.B[3]=WgT; g.C[3]=gbuf; g.epi[3]=EPI_SILU; g.obf[3]=0;
      mgemm_k<<<dim3(16,16,4), 256, 0, stream>>>(g); }
    { GemmArgs g{}; g.M=1024; g.N=64; g.K=1024;
      g.A[0]=xw; g.B[0]=dw1T; g.C[0]=hdecb; g.epi[0]=EPI_TANH; g.obf[0]=1;
      mgemm_k<<<dim3(1,16,1), 256, 0, stream>>>(g); }
    { GemmArgs g{}; g.M=1024; g.N=1024; g.K=64;
      g.A[0]=hdecb; g.B[0]=dw2T; g.C[0]=wlogb; g.epi[0]=EPI_WLOG; g.obf[0]=0; g.p1[0]=tdecay;
      mgemm_k<<<dim3(16,16,1), 256, 0, stream>>>(g); }
    chunkwise_k<<<32, 256, 0, stream>>>(rb, kb, vb, wlogb, faaaa, state0, ybuf, stout);
    gn_stats_k<<<dim3(16,32), 256, 0, stream>>>(ybuf, gnpart);
    gn_reduce_k<<<1, 256, 0, stream>>>(gnpart, gnstat);
    gn_apply_k<<<4096, 256, 0, stream>>>(ybuf, gbuf, gnstat, lnx_s, lnx_b, zbuf);
    { GemmArgs g{}; g.M=1024; g.N=1024; g.K=1024;
      g.A[0]=zbuf; g.B[0]=WoT; g.C[0]=x2buf; g.epi[0]=EPI_ADDRES; g.obf[0]=0; g.p1[0]=x;
      mgemm_k<<<dim3(16,16,1), 256, 0, stream>>>(g); }

    // ---- channel mixing ----
    ln_rows_k<<<1024, 256, 0, stream>>>(x2buf, ln2_s, ln2_b, xn);
    mix_ch_k<<<4096, 256, 0, stream>>>(xn, maa_kch, maa_rch, akb, arb);
    { GemmArgs g{}; g.M=1024; g.N=4096; g.K=1024;
      g.A[0]=akb; g.B[0]=WkchT; g.C[0]=kkb; g.epi[0]=EPI_RELU2; g.obf[0]=1;
      mgemm_k<<<dim3(64,16,1), 256, 0, stream>>>(g); }
    { GemmArgs g{}; g.M=1024; g.N=1024; g.K=4096;
      g.A[0]=kkb; g.B[0]=WvchT; g.C[0]=kvb; g.epi[0]=EPI_NONE; g.obf[0]=0;
      mgemm_k<<<dim3(16,16,1), 256, 0, stream>>>(g); }
    { GemmArgs g{}; g.M=1024; g.N=1024; g.K=1024;
      g.A[0]=arb; g.B[0]=WrchT; g.C[0]=out; g.epi[0]=EPI_SIGMUL; g.obf[0]=0;
      g.p1[0]=kvb; g.p2[0]=x2buf;
      mgemm_k<<<dim3(16,16,1), 256, 0, stream>>>(g); }
}

// Round 3
// 372.530 us; speedup vs baseline: 5.7693x; 1.6364x over previous
//
#include <hip/hip_runtime.h>
#include <math.h>

// RWKV block forward, MI355X — round 2: MFMA chunkwise scan (bf16 fragments,
// fp32 state), everything else identical to round 1.
// B=2 T=512 E=1024 H=16 Sh=64 D=1024 F=4096 CHUNK=64
#define T_  512
#define E_  1024
#define BTE 1048576   // B*T*E elements

enum { EPI_NONE=0, EPI_TANH=1, EPI_SILU=2, EPI_RELU2=3, EPI_WLOG=4, EPI_ADDRES=5, EPI_SIGMUL=6 };

typedef __attribute__((ext_vector_type(8))) short bf16x8;
typedef __attribute__((ext_vector_type(4))) float f32x4;

__device__ __forceinline__ unsigned short f2bf(float f) {
    union { float f; unsigned u; } v; v.f = f;
    unsigned r = v.u + 0x7fffu + ((v.u >> 16) & 1u);
    return (unsigned short)(r >> 16);
}
__device__ __forceinline__ float bf2f(unsigned short h) {
    union { unsigned u; float f; } v; v.u = ((unsigned)h) << 16;
    return v.f;
}

// ---------------- LayerNorm over rows of length 1024 (fp32 out) ----------------
__global__ __launch_bounds__(256) void ln_rows_k(const float* __restrict__ x,
        const float* __restrict__ sc, const float* __restrict__ bi,
        float* __restrict__ out)
{
    const int row = blockIdx.x;
    const int tid = threadIdx.x;
    const float* xr = x + (size_t)row * E_;
    float4 v = *reinterpret_cast<const float4*>(xr + tid*4);
    float s  = v.x + v.y + v.z + v.w;
    float ss = v.x*v.x + v.y*v.y + v.z*v.z + v.w*v.w;
    #pragma unroll
    for (int off = 32; off > 0; off >>= 1) {
        s  += __shfl_down(s, off);
        ss += __shfl_down(ss, off);
    }
    __shared__ float ps[4], pss[4];
    __shared__ float smu, srstd;
    if ((tid & 63) == 0) { ps[tid>>6] = s; pss[tid>>6] = ss; }
    __syncthreads();
    if (tid == 0) {
        float S  = ps[0]+ps[1]+ps[2]+ps[3];
        float SS = pss[0]+pss[1]+pss[2]+pss[3];
        float mu  = S * (1.f/E_);
        float var = SS * (1.f/E_) - mu*mu;
        smu = mu; srstd = rsqrtf(var + 1e-5f);
    }
    __syncthreads();
    const float mu = smu, rstd = srstd;
    float4 s4 = *reinterpret_cast<const float4*>(sc + tid*4);
    float4 b4 = *reinterpret_cast<const float4*>(bi + tid*4);
    float4 o;
    o.x = (v.x-mu)*rstd*s4.x + b4.x;
    o.y = (v.y-mu)*rstd*s4.y + b4.y;
    o.z = (v.z-mu)*rstd*s4.z + b4.z;
    o.w = (v.w-mu)*rstd*s4.w + b4.w;
    *reinterpret_cast<float4*>(out + (size_t)row*E_ + tid*4) = o;
}

// ---------------- xmix = xn + (shift(xn)-xn)*maa_x  (bf16 out) ----------------
__global__ __launch_bounds__(256) void mix_x_k(const float* __restrict__ xn,
        const float* __restrict__ maa, unsigned short* __restrict__ out)
{
    int idx = blockIdx.x*256 + threadIdx.x;     // < BTE
    int e = idx & 1023;
    int t = (idx >> 10) & 511;
    float xv = xn[idx];
    float prev = t ? xn[idx - E_] : 0.f;
    out[idx] = f2bf(xv + (prev - xv) * maa[e]);
}

// ---------------- channel-mix shift: ak/ar (bf16 out) ----------------
__global__ __launch_bounds__(256) void mix_ch_k(const float* __restrict__ xn2,
        const float* __restrict__ maaK, const float* __restrict__ maaR,
        unsigned short* __restrict__ ak, unsigned short* __restrict__ ar)
{
    int idx = blockIdx.x*256 + threadIdx.x;
    int e = idx & 1023;
    int t = (idx >> 10) & 511;
    float xv = xn2[idx];
    float prev = t ? xn2[idx - E_] : 0.f;
    float sxv = prev - xv;
    ak[idx] = f2bf(xv + sxv * maaK[e]);
    ar[idx] = f2bf(xv + sxv * maaR[e]);
}

// ---------------- mix5: xw/xk/xv/xr/xg from t5 @ W2 (reshape quirk), bf16 out ----------------
__global__ __launch_bounds__(256) void mix5_k(const float* __restrict__ xn,
        const float* __restrict__ t5, const float* __restrict__ W2,
        const float* __restrict__ maaW, const float* __restrict__ maaK,
        const float* __restrict__ maaV, const float* __restrict__ maaR,
        const float* __restrict__ maaG,
        unsigned short* __restrict__ xw, unsigned short* __restrict__ xk,
        unsigned short* __restrict__ xv, unsigned short* __restrict__ xr,
        unsigned short* __restrict__ xg)
{
    const int bt = blockIdx.x;
    const int b = bt >> 9, t = bt & 511;
    __shared__ float st5[5][32];
    __shared__ int sgs[5];
    const int tid = threadIdx.x;
    if (tid < 160) {
        int o = tid >> 5, c = tid & 31;
        int L = o*2 + b;
        int bs = L / 5, gs = L - bs*5;
        st5[o][c] = t5[((size_t)(bs*T_ + t))*160 + gs*32 + c];
        if (c == 0) sgs[o] = gs;
    }
    __syncthreads();
    const float* xnrow = xn + (size_t)bt*E_;
    const int g0=sgs[0], g1=sgs[1], g2=sgs[2], g3=sgs[3], g4=sgs[4];
    for (int e = tid; e < E_; e += 256) {
        float xnv = xnrow[e];
        float prev = (t > 0) ? xnrow[e - E_] : 0.f;
        float sxv = prev - xnv;
        float m0=0.f, m1=0.f, m2=0.f, m3=0.f, m4=0.f;
        #pragma unroll 4
        for (int c = 0; c < 32; ++c) {
            float a0 = st5[0][c], a1 = st5[1][c], a2 = st5[2][c], a3 = st5[3][c], a4 = st5[4][c];
            m0 += a0 * W2[((size_t)g0*32 + c)*E_ + e];
            m1 += a1 * W2[((size_t)g1*32 + c)*E_ + e];
            m2 += a2 * W2[((size_t)g2*32 + c)*E_ + e];
            m3 += a3 * W2[((size_t)g3*32 + c)*E_ + e];
            m4 += a4 * W2[((size_t)g4*32 + c)*E_ + e];
        }
        size_t oidx = (size_t)bt*E_ + e;
        xw[oidx] = f2bf(xnv + sxv*(maaW[e] + m0));
        xk[oidx] = f2bf(xnv + sxv*(maaK[e] + m1));
        xv[oidx] = f2bf(xnv + sxv*(maaV[e] + m2));
        xr[oidx] = f2bf(xnv + sxv*(maaR[e] + m3));
        xg[oidx] = f2bf(xnv + sxv*(maaG[e] + m4));
    }
}

// ---------------- weight convert+transpose: dst[n][k] = bf16(src[k][n]) ----------------
struct TransArgs {
    const float* src[6];
    unsigned short* dst[6];
    int K, N, Npad;
};
__global__ __launch_bounds__(256) void wtrans_k(TransArgs a)
{
    const int z = blockIdx.z;
    const float* S = a.src[z];
    unsigned short* D = a.dst[z];
    __shared__ float t[64][65];
    const int tid = threadIdx.x;
    const int k0 = blockIdx.y*64, n0 = blockIdx.x*64;
    #pragma unroll
    for (int i = 0; i < 16; ++i) {
        int r = i*4 + (tid >> 6), c = tid & 63;
        int gk = k0 + r, gn = n0 + c;
        t[r][c] = (gk < a.K && gn < a.N) ? S[(size_t)gk*a.N + gn] : 0.f;
    }
    __syncthreads();
    #pragma unroll
    for (int i = 0; i < 16; ++i) {
        int r = i*4 + (tid >> 6), c = tid & 63;
        int gn = n0 + r, gk = k0 + c;
        if (gn < a.Npad && gk < a.K)
            D[(size_t)gn*a.K + gk] = f2bf(t[c][r]);
    }
}

// ---------------- bf16 MFMA GEMM (unchanged from round 1) ----------------
struct GemmArgs {
    const unsigned short* A[4];
    const unsigned short* B[4];
    void* C[4];
    const float* p1[4];
    const float* p2[4];
    int epi[4];
    int obf[4];
    int M, N, K;
};
__global__ __launch_bounds__(256) void mgemm_k(GemmArgs g)
{
    const int bz = blockIdx.z;
    const unsigned short* Ag = g.A[bz];
    const unsigned short* BT = g.B[bz];
    const int N = g.N, K = g.K;
    const int m0 = blockIdx.y * 64, n0 = blockIdx.x * 64;
    const int tid = threadIdx.x;
    const int lane = tid & 63, w = tid >> 6;

    __shared__ __align__(16) unsigned short As[2][4096];
    __shared__ __align__(16) unsigned short Bs[2][4096];

    const size_t rowBytes = (size_t)K * 2;
    int sI[4], sIsB[4]; size_t sOff[4];
    #pragma unroll
    for (int ii = 0; ii < 4; ++ii) {
        int t = w*4 + ii;
        int isB = t >> 3;
        int i = t & 7;
        int r = i*8 + (lane >> 3);
        int gb = ((lane & 7) * 16) ^ ((r & 7) << 4);
        sI[ii] = i; sIsB[ii] = isB;
        int srow = (isB ? n0 : m0) + r;
        sOff[ii] = (size_t)srow * rowBytes + gb;
    }
    auto stage = [&](int buf, int k0) {
        const char* Abase = (const char*)Ag + (size_t)k0 * 2;
        const char* Bbase = (const char*)BT + (size_t)k0 * 2;
        #pragma unroll
        for (int ii = 0; ii < 4; ++ii) {
            const char* src = (sIsB[ii] ? Bbase : Abase) + sOff[ii];
            unsigned short* dst = (sIsB[ii] ? Bs[buf] : As[buf]) + sI[ii]*512;
            auto g1 = (const __attribute__((address_space(1))) unsigned int*)(src);
            auto l3 = (__attribute__((address_space(3))) unsigned int*)(uintptr_t)(dst);
            __builtin_amdgcn_global_load_lds(g1, l3, 16, 0, 0);
        }
    };

    const int wm = (w >> 1) * 32, wn = (w & 1) * 32;
    const int lr = lane & 15, lk = lane >> 4;
    int aoff[2][2], boff[2][2];
    #pragma unroll
    for (int mi = 0; mi < 2; ++mi)
        #pragma unroll
        for (int kw = 0; kw < 2; ++kw) {
            int ar = wm + mi*16 + lr;
            aoff[mi][kw] = ar*128 + ((kw*64 + lk*16) ^ ((ar & 7) << 4));
            int br = wn + mi*16 + lr;
            boff[mi][kw] = br*128 + ((kw*64 + lk*16) ^ ((br & 7) << 4));
        }

    f32x4 acc[2][2] = {};
    stage(0, 0);
    const int nk = K >> 6;
    int cur = 0;
    for (int kt = 0; kt < nk; ++kt) {
        __syncthreads();
        if (kt + 1 < nk) stage(cur ^ 1, (kt + 1) << 6);
        const char* Ab = (const char*)As[cur];
        const char* Bb = (const char*)Bs[cur];
        bf16x8 af[2][2], bfv[2][2];
        #pragma unroll
        for (int mi = 0; mi < 2; ++mi)
            #pragma unroll
            for (int kw = 0; kw < 2; ++kw) {
                af[mi][kw]  = *(const bf16x8*)(Ab + aoff[mi][kw]);
                bfv[mi][kw] = *(const bf16x8*)(Bb + boff[mi][kw]);
            }
        #pragma unroll
        for (int kw = 0; kw < 2; ++kw)
            #pragma unroll
            for (int mi = 0; mi < 2; ++mi)
                #pragma unroll
                for (int ni = 0; ni < 2; ++ni)
                    acc[mi][ni] = __builtin_amdgcn_mfma_f32_16x16x32_bf16(
                        af[mi][kw], bfv[ni][kw], acc[mi][ni], 0, 0, 0);
        cur ^= 1;
    }

    const int epi = g.epi[bz], obf = g.obf[bz];
    const float* p1 = g.p1[bz];
    const float* p2 = g.p2[bz];
    float* Cf = (float*)g.C[bz];
    unsigned short* Ch = (unsigned short*)g.C[bz];
    #pragma unroll
    for (int mi = 0; mi < 2; ++mi) {
        #pragma unroll
        for (int ni = 0; ni < 2; ++ni) {
            #pragma unroll
            for (int j = 0; j < 4; ++j) {
                int gm = m0 + wm + mi*16 + lk*4 + j;
                int gn = n0 + wn + ni*16 + lr;
                if (gn >= N) continue;
                size_t idx = (size_t)gm * N + gn;
                float a = acc[mi][ni][j];
                float o = a;
                if (epi == EPI_TANH)        o = tanhf(a);
                else if (epi == EPI_SILU)   o = a / (1.f + expf(-a));
                else if (epi == EPI_RELU2)  { float r = fmaxf(a, 0.f); o = r*r; }
                else if (epi == EPI_WLOG) {
                    float z = -(p1[gn] + a);
                    float sp = (z > 15.f) ? z : log1pf(expf(z));
                    o = logf(fminf(fmaxf(sp, 1e-6f), 1.f));
                }
                else if (epi == EPI_ADDRES) o = a + p1[idx];
                else if (epi == EPI_SIGMUL) o = p2[idx] + p1[idx] / (1.f + expf(-a));
                if (obf) Ch[idx] = f2bf(o); else Cf[idx] = o;
            }
        }
    }
}

// ---------------- chunkwise RWKV scan — MFMA version ----------------
// Same factored algebra as round 1 (verified passing), six 64x64x64 matmuls per
// chunk now on the matrix pipe with bf16 fragments:
//   Q  = RD @ KA2^T          (KA2 = k*exp(-A))          -> masked (tril -1, diag=udiag)
//   P  = RD @ KA^T                                      -> masked (tril -1)
//   Yintra = QM @ V          Yloc = PM @ VX             YS = RD @ S0
//   U  = KA^T @ VX           y = Yintra + BF*(YS+Yloc)  S' = B63*(S + U)
// bf16 LDS matrices: 64 rows x 128B, XOR swizzle byte ^= ((row&7)<<4) — identical
// fragment addressing to mgemm_k (verified). State kept f32, transposed [k][j].
#define SWZI(r, c)  (((r) << 6) + ((c) ^ (((r) & 7) << 3)))           // ushort units
#define FIDX(r, kw) (((r) << 6) + ((((kw)*32) + fk*8) ^ (((r) & 7) << 3)))
__global__ __launch_bounds__(256) void chunkwise_k(
    const unsigned short* __restrict__ rb, const unsigned short* __restrict__ kb,
    const unsigned short* __restrict__ vb, const float* __restrict__ wb,
    const float* __restrict__ faaaa, const float* __restrict__ st_in,
    float* __restrict__ yb, float* __restrict__ st_out)
{
    const int bh = blockIdx.x;            // b*16 + h
    const int b = bh >> 4, h = bh & 15;
    const int tid = threadIdx.x;
    const int l = tid & 63, w = tid >> 6;
    const int jl = l, q = w;
    const int fr = l & 15, fk = l >> 4;   // fragment row-in-16 / k-group
    const int wm = (w >> 1) * 32, wn = (w & 1) * 32;

    __shared__ float sA [64*68];          // A_intra cumsum; becomes BF in phase C
    __shared__ float sPP[64*68];          // r*u*k staging for udiag
    __shared__ float sST[64*68];          // state f32, TRANSPOSED: [k][j]
    __shared__ float sUD[64];
    __shared__ float sB63[64];
    __shared__ float sQS[4][64];
    __shared__ __align__(16) unsigned short sRDb [4096];
    __shared__ __align__(16) unsigned short sKAb [4096];
    __shared__ __align__(16) unsigned short sKA2b[4096];
    __shared__ __align__(16) unsigned short sKATb[4096];
    __shared__ __align__(16) unsigned short sVTb [4096];
    __shared__ __align__(16) unsigned short sVXTb[4096];
    __shared__ __align__(16) unsigned short sSTb [4096];
    __shared__ __align__(16) unsigned short sQMb [4096];
    __shared__ __align__(16) unsigned short sPMb [4096];

    // load state transposed: sST[k][j] = st_in[bh, j, k]
    for (int i = tid; i < 4096; i += 256) {
        int j = i >> 6, k = i & 63;
        sST[k*68 + j] = st_in[(size_t)bh*4096 + i];
    }
    const float u_reg = faaaa[h*64 + jl];
    const size_t base = (size_t)b*T_*E_ + (size_t)h*64;
    __syncthreads();

    for (int nc = 0; nc < 8; ++nc) {
        const int t0 = nc*64;

        // ---- phase 0: sSTb (bf16, swizzled) from f32 sST ----
        {
            int k = tid >> 2, j0 = (tid & 3) * 16;
            const float* src = &sST[k*68 + j0];
            #pragma unroll
            for (int hf = 0; hf < 2; ++hf) {
                bf16x8 tmp;
                #pragma unroll
                for (int e = 0; e < 8; ++e) tmp[e] = (short)f2bf(src[hf*8 + e]);
                *(bf16x8*)(&sSTb[SWZI(k, j0 + hf*8)]) = tmp;
            }
        }

        // ---- A1: A = cumsum_t(wlog) -> sA ----
        float vreg[16];
        {
            float loc[16]; float cum = 0.f;
            #pragma unroll
            for (int c = 0; c < 16; ++c) {
                float wv = wb[base + (size_t)(t0 + q*16 + c)*E_ + jl];
                cum += wv; loc[c] = cum;
            }
            sQS[q][jl] = cum;
            __syncthreads();
            float pre = 0.f;
            for (int qq = 0; qq < q; ++qq) pre += sQS[qq][jl];
            #pragma unroll
            for (int c = 0; c < 16; ++c) sA[(q*16 + c)*68 + jl] = loc[c] + pre;
        }
        __syncthreads();

        // ---- A2: build RD/KA/KA2/KAT/VT (bf16) + r*u*k staging ----
        {
            const float atot = sA[63*68 + jl];
            #pragma unroll
            for (int c = 0; c < 16; ++c) {
                const int t = q*16 + c;
                const size_t gi = base + (size_t)(t0 + t)*E_ + jl;
                const float rv = bf2f(rb[gi]), kv = bf2f(kb[gi]), vv = bf2f(vb[gi]);
                vreg[c] = vv;
                const float a = sA[t*68 + jl];
                const float aprev = (t > 0) ? sA[(t-1)*68 + jl] : 0.f;
                sRDb [SWZI(t, jl)] = f2bf(rv * expf(aprev));
                const float ka = kv * expf(atot - a);
                sKAb [SWZI(t, jl)] = f2bf(ka);
                sKA2b[SWZI(t, jl)] = f2bf(kv * expf(-a));
                sKATb[SWZI(jl, t)] = f2bf(ka);
                sVTb [SWZI(jl, t)] = f2bf(vv);
                sPP[t*68 + jl] = rv * u_reg * kv;
            }
        }
        __syncthreads();

        // ---- udiag reduce: sUD[t] = sum_j r*u*k ----
        {
            int row = q*16 + (l & 15);
            const float* pp = &sPP[row*68 + (l >> 4)*16];
            float s = 0.f;
            #pragma unroll
            for (int e = 0; e < 16; ++e) s += pp[e];
            s += __shfl_down(s, 16);
            s += __shfl_down(s, 32);
            if ((l >> 4) == 0) sUD[row] = s;
        }

        // ---- B: MFMA Q = RD@KA2^T, P = RD@KA^T ----
        f32x4 accQ[2][2] = {}, accP[2][2] = {};
        #pragma unroll
        for (int kw = 0; kw < 2; ++kw) {
            bf16x8 ar[2], bka[2], bk2[2];
            #pragma unroll
            for (int mi = 0; mi < 2; ++mi)
                ar[mi] = *(const bf16x8*)(&sRDb[FIDX(wm + mi*16 + fr, kw)]);
            #pragma unroll
            for (int ni = 0; ni < 2; ++ni) {
                bka[ni] = *(const bf16x8*)(&sKAb [FIDX(wn + ni*16 + fr, kw)]);
                bk2[ni] = *(const bf16x8*)(&sKA2b[FIDX(wn + ni*16 + fr, kw)]);
            }
            #pragma unroll
            for (int mi = 0; mi < 2; ++mi)
                #pragma unroll
                for (int ni = 0; ni < 2; ++ni) {
                    accQ[mi][ni] = __builtin_amdgcn_mfma_f32_16x16x32_bf16(ar[mi], bk2[ni], accQ[mi][ni], 0,0,0);
                    accP[mi][ni] = __builtin_amdgcn_mfma_f32_16x16x32_bf16(ar[mi], bka[ni], accP[mi][ni], 0,0,0);
                }
        }
        __syncthreads();   // sUD ready; QM/PM writes ordered vs readers by C syncs

        // ---- masked C-layout -> bf16 LDS: QM (tril-1 + udiag on diag), PM (tril-1) ----
        #pragma unroll
        for (int mi = 0; mi < 2; ++mi)
            #pragma unroll
            for (int ni = 0; ni < 2; ++ni)
                #pragma unroll
                for (int reg = 0; reg < 4; ++reg) {
                    int t = wm + mi*16 + fk*4 + reg;
                    int s = wn + ni*16 + fr;
                    float qv = (s < t) ? accQ[mi][ni][reg] : ((s == t) ? sUD[t] : 0.f);
                    float pv = (s < t) ? accP[mi][ni][reg] : 0.f;
                    sQMb[SWZI(t, s)] = f2bf(qv);
                    sPMb[SWZI(t, s)] = f2bf(pv);
                }

        // ---- C: Bcum = cumsum_t(A); sA <- BF; build VXT; B63 ----
        {
            float loc2[16]; float cum2 = 0.f;
            #pragma unroll
            for (int c = 0; c < 16; ++c) {
                cum2 += sA[(q*16 + c)*68 + jl];
                loc2[c] = cum2;
            }
            sQS[q][jl] = cum2;
            __syncthreads();
            float pre2 = 0.f;
            for (int qq = 0; qq < q; ++qq) pre2 += sQS[qq][jl];
            #pragma unroll
            for (int c = 0; c < 16; ++c) {
                const int t = q*16 + c;
                const float Bv = loc2[c] + pre2;
                const float Bprev = (c > 0) ? (loc2[c-1] + pre2) : pre2;
                sA[t*68 + jl] = expf(Bprev);                       // BF[t] = exp(Bcum[t-1])
                sVXTb[SWZI(jl, t)] = f2bf(vreg[c] * expf(-Bv));
                if (t == 63) sB63[jl] = expf(Bv);
            }
        }
        __syncthreads();

        // ---- D: MFMA Yintra(QM,VT) + Yloc(PM,VXT) + YS(RD,STb) + U(KAT,VXT) ----
        {
            f32x4 accI[2][2] = {}, accL[2][2] = {}, accS[2][2] = {}, accU[2][2] = {};
            #pragma unroll
            for (int kw = 0; kw < 2; ++kw) {
                bf16x8 aQ[2], aP[2], aR[2], aK[2], bV[2], bX[2], bS[2];
                #pragma unroll
                for (int mi = 0; mi < 2; ++mi) {
                    int rA = wm + mi*16 + fr;
                    aQ[mi] = *(const bf16x8*)(&sQMb [FIDX(rA, kw)]);
                    aP[mi] = *(const bf16x8*)(&sPMb [FIDX(rA, kw)]);
                    aR[mi] = *(const bf16x8*)(&sRDb [FIDX(rA, kw)]);
                    aK[mi] = *(const bf16x8*)(&sKATb[FIDX(rA, kw)]);
                }
                #pragma unroll
                for (int ni = 0; ni < 2; ++ni) {
                    int rB = wn + ni*16 + fr;
                    bV[ni] = *(const bf16x8*)(&sVTb [FIDX(rB, kw)]);
                    bX[ni] = *(const bf16x8*)(&sVXTb[FIDX(rB, kw)]);
                    bS[ni] = *(const bf16x8*)(&sSTb [FIDX(rB, kw)]);
                }
                #pragma unroll
                for (int mi = 0; mi < 2; ++mi)
                    #pragma unroll
                    for (int ni = 0; ni < 2; ++ni) {
                        accI[mi][ni] = __builtin_amdgcn_mfma_f32_16x16x32_bf16(aQ[mi], bV[ni], accI[mi][ni], 0,0,0);
                        accL[mi][ni] = __builtin_amdgcn_mfma_f32_16x16x32_bf16(aP[mi], bX[ni], accL[mi][ni], 0,0,0);
                        accS[mi][ni] = __builtin_amdgcn_mfma_f32_16x16x32_bf16(aR[mi], bS[ni], accS[mi][ni], 0,0,0);
                        accU[mi][ni] = __builtin_amdgcn_mfma_f32_16x16x32_bf16(aK[mi], bX[ni], accU[mi][ni], 0,0,0);
                    }
            }
            // y = Yintra + BF*(YS + Yloc)
            #pragma unroll
            for (int mi = 0; mi < 2; ++mi)
                #pragma unroll
                for (int ni = 0; ni < 2; ++ni)
                    #pragma unroll
                    for (int reg = 0; reg < 4; ++reg) {
                        int t = wm + mi*16 + fk*4 + reg;
                        int k = wn + ni*16 + fr;
                        float bfv = sA[t*68 + k];
                        float yv = accI[mi][ni][reg] + bfv*(accS[mi][ni][reg] + accL[mi][ni][reg]);
                        yb[base + (size_t)(t0 + t)*E_ + k] = yv;
                    }
            // S' = B63[k] * (S + U)   (state transposed: sST[k][j])
            #pragma unroll
            for (int mi = 0; mi < 2; ++mi)
                #pragma unroll
                for (int ni = 0; ni < 2; ++ni)
                    #pragma unroll
                    for (int reg = 0; reg < 4; ++reg) {
                        int j = wm + mi*16 + fk*4 + reg;
                        int k = wn + ni*16 + fr;
                        int si = k*68 + j;
                        sST[si] = sB63[k] * (sST[si] + accU[mi][ni][reg]);
                    }
        }
        __syncthreads();
    }

    for (int i = tid; i < 4096; i += 256) {
        int j = i >> 6, k = i & 63;
        st_out[(size_t)bh*4096 + i] = sST[k*68 + j];
    }
}

// ---------------- GroupNorm (global stats per head) ----------------
__global__ __launch_bounds__(256) void gn_stats_k(const float* __restrict__ y,
        float* __restrict__ part)
{
    const int h = blockIdx.x, slab = blockIdx.y;
    const int tid = threadIdx.x;
    float s = 0.f, ss = 0.f;
    for (int i = tid; i < 2048; i += 256) {
        int r = slab*32 + (i >> 6), k = i & 63;
        float v = y[(size_t)r*E_ + h*64 + k];
        s += v; ss += v*v;
    }
    #pragma unroll
    for (int off = 32; off > 0; off >>= 1) {
        s  += __shfl_down(s, off);
        ss += __shfl_down(ss, off);
    }
    __shared__ float ps[4], pss[4];
    if ((tid & 63) == 0) { ps[tid>>6] = s; pss[tid>>6] = ss; }
    __syncthreads();
    if (tid == 0) {
        part[h*32 + slab]       = ps[0]+ps[1]+ps[2]+ps[3];
        part[512 + h*32 + slab] = pss[0]+pss[1]+pss[2]+pss[3];
    }
}

__global__ __launch_bounds__(256) void gn_reduce_k(const float* __restrict__ part,
        float* __restrict__ stats)
{
    int tid = threadIdx.x;
    if (tid < 16) {
        float s = 0.f, ss = 0.f;
        for (int sl = 0; sl < 32; ++sl) {
            s  += part[tid*32 + sl];
            ss += part[512 + tid*32 + sl];
        }
        float mu  = s * (1.f/65536.f);
        float var = ss * (1.f/65536.f) - mu*mu;
        stats[tid]      = mu;
        stats[16 + tid] = rsqrtf(var + 1e-5f);
    }
}

__global__ __launch_bounds__(256) void gn_apply_k(const float* __restrict__ y,
        const float* __restrict__ g, const float* __restrict__ stats,
        const float* __restrict__ sc, const float* __restrict__ bi,
        unsigned short* __restrict__ z)
{
    int idx = blockIdx.x*256 + threadIdx.x;
    int d = idx & 1023;
    int h = d >> 6;
    float mu = stats[h], rstd = stats[16 + h];
    float yn = (y[idx] - mu)*rstd*sc[d] + bi[d];
    z[idx] = f2bf(yn * g[idx]);
}

// ---------------- launch ----------------
extern "C" void kernel_launch(void* const* d_in, const int* in_sizes, int n_in,
                              void* d_out, int out_size, void* d_ws, size_t ws_size,
                              hipStream_t stream)
{
    const float* x       = (const float*)d_in[0];
    const float* state0  = (const float*)d_in[1];
    const float* maa_x   = (const float*)d_in[2];
    const float* maa_w   = (const float*)d_in[3];
    const float* maa_k   = (const float*)d_in[4];
    const float* maa_v   = (const float*)d_in[5];
    const float* maa_r   = (const float*)d_in[6];
    const float* maa_g   = (const float*)d_in[7];
    const float* tdecay  = (const float*)d_in[8];
    const float* faaaa   = (const float*)d_in[9];
    const float* w1      = (const float*)d_in[10];
    const float* w2      = (const float*)d_in[11];
    const float* dw1     = (const float*)d_in[12];
    const float* dw2     = (const float*)d_in[13];
    const float* Wr      = (const float*)d_in[14];
    const float* Wk      = (const float*)d_in[15];
    const float* Wv      = (const float*)d_in[16];
    const float* Wg      = (const float*)d_in[17];
    const float* Wo      = (const float*)d_in[18];
    const float* lnx_s   = (const float*)d_in[19];
    const float* lnx_b   = (const float*)d_in[20];
    const float* maa_kch = (const float*)d_in[21];
    const float* maa_rch = (const float*)d_in[22];
    const float* Wk_ch   = (const float*)d_in[23];
    const float* Wv_ch   = (const float*)d_in[24];
    const float* Wr_ch   = (const float*)d_in[25];
    const float* ln1_s   = (const float*)d_in[26];
    const float* ln1_b   = (const float*)d_in[27];
    const float* ln2_s   = (const float*)d_in[28];
    const float* ln2_b   = (const float*)d_in[29];

    // ---- workspace layout ----
    float* xn     = (float*)d_ws;               // 1M f32 (reused as xn2)
    float* t5     = xn + 1048576;               // 163840
    float* gbuf   = t5 + 163840;                // 1M
    float* wlogb  = gbuf + 1048576;             // 1M
    float* ybuf   = wlogb + 1048576;            // 1M
    float* kvb    = ybuf + 1048576;             // 1M
    float* gnpart = kvb + 1048576;              // 1024
    float* gnstat = gnpart + 1024;              // 32
    unsigned short* u = (unsigned short*)(gnstat + 32);
    unsigned short* xmix = u;  u += 1048576;    // reused as z
    unsigned short* xw   = u;  u += 1048576;    // reused as ak
    unsigned short* xk   = u;  u += 1048576;    // reused as ar
    unsigned short* xv_  = u;  u += 1048576;    // kk[0:1M]
    unsigned short* xr   = u;  u += 1048576;    // kk[1M:2M]
    unsigned short* xg   = u;  u += 1048576;    // kk[2M:3M]
    /* kk extra 1M */          u += 1048576;    // kk[3M:4M]
    unsigned short* rb   = u;  u += 1048576;
    unsigned short* kb   = u;  u += 1048576;
    unsigned short* vb   = u;  u += 1048576;
    unsigned short* hdecb= u;  u += 65536;
    unsigned short* WrT  = u;  u += 1048576;
    unsigned short* WkT  = u;  u += 1048576;
    unsigned short* WvT  = u;  u += 1048576;
    unsigned short* WgT  = u;  u += 1048576;
    unsigned short* WoT  = u;  u += 1048576;
    unsigned short* WrchT= u;  u += 1048576;
    unsigned short* WkchT= u;  u += 4194304;    // 4096 x 1024
    unsigned short* WvchT= u;  u += 4194304;    // 1024 x 4096
    unsigned short* w1T  = u;  u += 196608;     // 192 x 1024
    unsigned short* dw1T = u;  u += 65536;      // 64 x 1024
    unsigned short* dw2T = u;  u += 65536;      // 1024 x 64
    unsigned short* zbuf = xmix;
    unsigned short* akb  = xw;
    unsigned short* arb  = xk;
    unsigned short* kkb  = xv_;                 // 4M contiguous

    float* out   = (float*)d_out;
    float* x2buf = out;                         // d_out reused as x2 scratch
    float* stout = out + (size_t)BTE;

    // ---- weight convert+transpose (once per launch) ----
    {
        TransArgs ta{}; ta.K = 1024; ta.N = 1024; ta.Npad = 1024;
        ta.src[0]=Wr; ta.src[1]=Wk; ta.src[2]=Wv; ta.src[3]=Wg; ta.src[4]=Wo; ta.src[5]=Wr_ch;
        ta.dst[0]=WrT; ta.dst[1]=WkT; ta.dst[2]=WvT; ta.dst[3]=WgT; ta.dst[4]=WoT; ta.dst[5]=WrchT;
        wtrans_k<<<dim3(16,16,6), 256, 0, stream>>>(ta);
    }
    { TransArgs ta{}; ta.K=1024; ta.N=4096; ta.Npad=4096; ta.src[0]=Wk_ch; ta.dst[0]=WkchT;
      wtrans_k<<<dim3(64,16,1), 256, 0, stream>>>(ta); }
    { TransArgs ta{}; ta.K=4096; ta.N=1024; ta.Npad=1024; ta.src[0]=Wv_ch; ta.dst[0]=WvchT;
      wtrans_k<<<dim3(16,64,1), 256, 0, stream>>>(ta); }
    { TransArgs ta{}; ta.K=1024; ta.N=160; ta.Npad=192; ta.src[0]=w1; ta.dst[0]=w1T;
      wtrans_k<<<dim3(3,16,1), 256, 0, stream>>>(ta); }
    { TransArgs ta{}; ta.K=1024; ta.N=64; ta.Npad=64; ta.src[0]=dw1; ta.dst[0]=dw1T;
      wtrans_k<<<dim3(1,16,1), 256, 0, stream>>>(ta); }
    { TransArgs ta{}; ta.K=64; ta.N=1024; ta.Npad=1024; ta.src[0]=dw2; ta.dst[0]=dw2T;
      wtrans_k<<<dim3(16,1,1), 256, 0, stream>>>(ta); }

    // ---- time mixing ----
    ln_rows_k<<<1024, 256, 0, stream>>>(x, ln1_s, ln1_b, xn);
    mix_x_k<<<4096, 256, 0, stream>>>(xn, maa_x, xmix);
    { GemmArgs g{}; g.M=1024; g.N=160; g.K=1024;
      g.A[0]=xmix; g.B[0]=w1T; g.C[0]=t5; g.epi[0]=EPI_TANH; g.obf[0]=0;
      mgemm_k<<<dim3(3,16,1), 256, 0, stream>>>(g); }
    mix5_k<<<1024, 256, 0, stream>>>(xn, t5, w2, maa_w, maa_k, maa_v, maa_r, maa_g,
                                     xw, xk, xv_, xr, xg);
    { GemmArgs g{}; g.M=1024; g.N=1024; g.K=1024;
      g.A[0]=xr;  g.B[0]=WrT; g.C[0]=rb;   g.epi[0]=EPI_NONE; g.obf[0]=1;
      g.A[1]=xk;  g.B[1]=WkT; g.C[1]=kb;   g.epi[1]=EPI_NONE; g.obf[1]=1;
      g.A[2]=xv_; g.B[2]=WvT; g.C[2]=vb;   g.epi[2]=EPI_NONE; g.obf[2]=1;
      g.A[3]=xg;  g.B[3]=WgT; g.C[3]=gbuf; g.epi[3]=EPI_SILU; g.obf[3]=0;
      mgemm_k<<<dim3(16,16,4), 256, 0, stream>>>(g); }
    { GemmArgs g{}; g.M=1024; g.N=64; g.K=1024;
      g.A[0]=xw; g.B[0]=dw1T; g.C[0]=hdecb; g.epi[0]=EPI_TANH; g.obf[0]=1;
      mgemm_k<<<dim3(1,16,1), 256, 0, stream>>>(g); }
    { GemmArgs g{}; g.M=1024; g.N=1024; g.K=64;
      g.A[0]=hdecb; g.B[0]=dw2T; g.C[0]=wlogb; g.epi[0]=EPI_WLOG; g.obf[0]=0; g.p1[0]=tdecay;
      mgemm_k<<<dim3(16,16,1), 256, 0, stream>>>(g); }
    chunkwise_k<<<32, 256, 0, stream>>>(rb, kb, vb, wlogb, faaaa, state0, ybuf, stout);
    gn_stats_k<<<dim3(16,32), 256, 0, stream>>>(ybuf, gnpart);
    gn_reduce_k<<<1, 256, 0, stream>>>(gnpart, gnstat);
    gn_apply_k<<<4096, 256, 0, stream>>>(ybuf, gbuf, gnstat, lnx_s, lnx_b, zbuf);
    { GemmArgs g{}; g.M=1024; g.N=1024; g.K=1024;
      g.A[0]=zbuf; g.B[0]=WoT; g.C[0]=x2buf; g.epi[0]=EPI_ADDRES; g.obf[0]=0; g.p1[0]=x;
      mgemm_k<<<dim3(16,16,1), 256, 0, stream>>>(g); }

    // ---- channel mixing ----
    ln_rows_k<<<1024, 256, 0, stream>>>(x2buf, ln2_s, ln2_b, xn);
    mix_ch_k<<<4096, 256, 0, stream>>>(xn, maa_kch, maa_rch, akb, arb);
    { GemmArgs g{}; g.M=1024; g.N=4096; g.K=1024;
      g.A[0]=akb; g.B[0]=WkchT; g.C[0]=kkb; g.epi[0]=EPI_RELU2; g.obf[0]=1;
      mgemm_k<<<dim3(64,16,1), 256, 0, stream>>>(g); }
    { GemmArgs g{}; g.M=1024; g.N=1024; g.K=4096;
      g.A[0]=kkb; g.B[0]=WvchT; g.C[0]=kvb; g.epi[0]=EPI_NONE; g.obf[0]=0;
      mgemm_k<<<dim3(16,16,1), 256, 0, stream>>>(g); }
    { GemmArgs g{}; g.M=1024; g.N=1024; g.K=1024;
      g.A[0]=arb; g.B[0]=WrchT; g.C[0]=out; g.epi[0]=EPI_SIGMUL; g.obf[0]=0;
      g.p1[0]=kvb; g.p2[0]=x2buf;
      mgemm_k<<<dim3(16,16,1), 256, 0, stream>>>(g); }
}

// Round 4
// 271.603 us; speedup vs baseline: 7.9131x; 1.3716x over previous
//
#include <hip/hip_runtime.h>
#include <math.h>

// RWKV block forward, MI355X — round 3: parallel chunkwise (pass1/scan/pass2)
// + mix5 as batched MFMA GEMM. B=2 T=512 E=1024 H=16 Sh=64 F=4096 CHUNK=64
#define T_  512
#define E_  1024
#define BTE 1048576

enum { EPI_NONE=0, EPI_TANH=1, EPI_SILU=2, EPI_RELU2=3, EPI_WLOG=4, EPI_ADDRES=5, EPI_SIGMUL=6 };

typedef __attribute__((ext_vector_type(8))) short bf16x8;
typedef __attribute__((ext_vector_type(4))) float f32x4;

__device__ __forceinline__ unsigned short f2bf(float f) {
    union { float f; unsigned u; } v; v.f = f;
    unsigned r = v.u + 0x7fffu + ((v.u >> 16) & 1u);
    return (unsigned short)(r >> 16);
}
__device__ __forceinline__ float bf2f(unsigned short h) {
    union { unsigned u; float f; } v; v.u = ((unsigned)h) << 16;
    return v.f;
}

// ---------------- LayerNorm over rows of length 1024 (fp32 out) ----------------
__global__ __launch_bounds__(256) void ln_rows_k(const float* __restrict__ x,
        const float* __restrict__ sc, const float* __restrict__ bi,
        float* __restrict__ out)
{
    const int row = blockIdx.x;
    const int tid = threadIdx.x;
    const float* xr = x + (size_t)row * E_;
    float4 v = *reinterpret_cast<const float4*>(xr + tid*4);
    float s  = v.x + v.y + v.z + v.w;
    float ss = v.x*v.x + v.y*v.y + v.z*v.z + v.w*v.w;
    #pragma unroll
    for (int off = 32; off > 0; off >>= 1) {
        s  += __shfl_down(s, off);
        ss += __shfl_down(ss, off);
    }
    __shared__ float ps[4], pss[4];
    __shared__ float smu, srstd;
    if ((tid & 63) == 0) { ps[tid>>6] = s; pss[tid>>6] = ss; }
    __syncthreads();
    if (tid == 0) {
        float S  = ps[0]+ps[1]+ps[2]+ps[3];
        float SS = pss[0]+pss[1]+pss[2]+pss[3];
        float mu  = S * (1.f/E_);
        float var = SS * (1.f/E_) - mu*mu;
        smu = mu; srstd = rsqrtf(var + 1e-5f);
    }
    __syncthreads();
    const float mu = smu, rstd = srstd;
    float4 s4 = *reinterpret_cast<const float4*>(sc + tid*4);
    float4 b4 = *reinterpret_cast<const float4*>(bi + tid*4);
    float4 o;
    o.x = (v.x-mu)*rstd*s4.x + b4.x;
    o.y = (v.y-mu)*rstd*s4.y + b4.y;
    o.z = (v.z-mu)*rstd*s4.z + b4.z;
    o.w = (v.w-mu)*rstd*s4.w + b4.w;
    *reinterpret_cast<float4*>(out + (size_t)row*E_ + tid*4) = o;
}

// ---------------- xmix = xn + (shift(xn)-xn)*maa_x  (bf16 out) ----------------
__global__ __launch_bounds__(256) void mix_x_k(const float* __restrict__ xn,
        const float* __restrict__ maa, unsigned short* __restrict__ out)
{
    int idx = blockIdx.x*256 + threadIdx.x;
    int e = idx & 1023;
    int t = (idx >> 10) & 511;
    float xv = xn[idx];
    float prev = t ? xn[idx - E_] : 0.f;
    out[idx] = f2bf(xv + (prev - xv) * maa[e]);
}

// ---------------- channel-mix shift: ak/ar (bf16 out) ----------------
__global__ __launch_bounds__(256) void mix_ch_k(const float* __restrict__ xn2,
        const float* __restrict__ maaK, const float* __restrict__ maaR,
        unsigned short* __restrict__ ak, unsigned short* __restrict__ ar)
{
    int idx = blockIdx.x*256 + threadIdx.x;
    int e = idx & 1023;
    int t = (idx >> 10) & 511;
    float xv = xn2[idx];
    float prev = t ? xn2[idx - E_] : 0.f;
    float sxv = prev - xv;
    ak[idx] = f2bf(xv + sxv * maaK[e]);
    ar[idx] = f2bf(xv + sxv * maaR[e]);
}

// ---------------- t5 repack: t5p[g][bt][k64] = bf16(t5[bt][g*32+k]), zero-pad ----------------
__global__ __launch_bounds__(256) void t5repack_k(const float* __restrict__ t5,
        unsigned short* __restrict__ t5p)
{
    int idx = blockIdx.x*256 + threadIdx.x;          // < 5*1024*64
    int c = idx & 63, bt = (idx >> 6) & 1023, g = idx >> 16;
    t5p[idx] = (c < 32) ? f2bf(t5[(size_t)bt*160 + g*32 + c]) : (unsigned short)0;
}

// ---------------- mix5 apply: xw/xk/xv/xr/xg from m (reshape quirk) ----------------
// m_o[b,t,e] comes from GEMM-g where L=o*2+b -> (b_src=L/5, g_src=L%5)
__global__ __launch_bounds__(256) void mix5_apply_k(const float* __restrict__ xn,
        const unsigned short* __restrict__ mb,
        const float* __restrict__ maaW, const float* __restrict__ maaK,
        const float* __restrict__ maaV, const float* __restrict__ maaR,
        const float* __restrict__ maaG,
        unsigned short* __restrict__ xw, unsigned short* __restrict__ xk,
        unsigned short* __restrict__ xv, unsigned short* __restrict__ xr,
        unsigned short* __restrict__ xg)
{
    int idx = blockIdx.x*256 + threadIdx.x;
    int e = idx & 1023;
    int bt = idx >> 10;
    int b = bt >> 9, t = bt & 511;
    float xnv = xn[idx];
    float prev = t ? xn[idx - E_] : 0.f;
    float sxv = prev - xnv;
    float m[5];
    #pragma unroll
    for (int o = 0; o < 5; ++o) {
        int L = o*2 + b;
        int bs = L / 5, gs = L - bs*5;
        m[o] = bf2f(mb[(size_t)gs*1048576 + (size_t)(bs*T_ + t)*E_ + e]);
    }
    xw[idx] = f2bf(xnv + sxv*(maaW[e] + m[0]));
    xk[idx] = f2bf(xnv + sxv*(maaK[e] + m[1]));
    xv[idx] = f2bf(xnv + sxv*(maaV[e] + m[2]));
    xr[idx] = f2bf(xnv + sxv*(maaR[e] + m[3]));
    xg[idx] = f2bf(xnv + sxv*(maaG[e] + m[4]));
}

// ---------------- weight convert+transpose: dst[n][kpad] = bf16(src[k][n]) ----------------
struct TransArgs {
    const float* src[6];
    unsigned short* dst[6];
    int K, N, Npad, Kpad;
};
__global__ __launch_bounds__(256) void wtrans_k(TransArgs a)
{
    const int z = blockIdx.z;
    const float* S = a.src[z];
    unsigned short* D = a.dst[z];
    __shared__ float t[64][65];
    const int tid = threadIdx.x;
    const int k0 = blockIdx.y*64, n0 = blockIdx.x*64;
    #pragma unroll
    for (int i = 0; i < 16; ++i) {
        int r = i*4 + (tid >> 6), c = tid & 63;
        int gk = k0 + r, gn = n0 + c;
        t[r][c] = (gk < a.K && gn < a.N) ? S[(size_t)gk*a.N + gn] : 0.f;
    }
    __syncthreads();
    #pragma unroll
    for (int i = 0; i < 16; ++i) {
        int r = i*4 + (tid >> 6), c = tid & 63;
        int gn = n0 + r, gk = k0 + c;
        if (gn < a.Npad && gk < a.Kpad)
            D[(size_t)gn*a.Kpad + gk] = f2bf(t[c][r]);
    }
}

// ---------------- bf16 MFMA GEMM (verified round 1/2) ----------------
struct GemmArgs {
    const unsigned short* A[5];
    const unsigned short* B[5];
    void* C[5];
    const float* p1[5];
    const float* p2[5];
    int epi[5];
    int obf[5];
    int M, N, K;
};
__global__ __launch_bounds__(256) void mgemm_k(GemmArgs g)
{
    const int bz = blockIdx.z;
    const unsigned short* Ag = g.A[bz];
    const unsigned short* BT = g.B[bz];
    const int N = g.N, K = g.K;
    const int m0 = blockIdx.y * 64, n0 = blockIdx.x * 64;
    const int tid = threadIdx.x;
    const int lane = tid & 63, w = tid >> 6;

    __shared__ __align__(16) unsigned short As[2][4096];
    __shared__ __align__(16) unsigned short Bs[2][4096];

    const size_t rowBytes = (size_t)K * 2;
    int sI[4], sIsB[4]; size_t sOff[4];
    #pragma unroll
    for (int ii = 0; ii < 4; ++ii) {
        int t = w*4 + ii;
        int isB = t >> 3;
        int i = t & 7;
        int r = i*8 + (lane >> 3);
        int gb = ((lane & 7) * 16) ^ ((r & 7) << 4);
        sI[ii] = i; sIsB[ii] = isB;
        int srow = (isB ? n0 : m0) + r;
        sOff[ii] = (size_t)srow * rowBytes + gb;
    }
    auto stage = [&](int buf, int k0) {
        const char* Abase = (const char*)Ag + (size_t)k0 * 2;
        const char* Bbase = (const char*)BT + (size_t)k0 * 2;
        #pragma unroll
        for (int ii = 0; ii < 4; ++ii) {
            const char* src = (sIsB[ii] ? Bbase : Abase) + sOff[ii];
            unsigned short* dst = (sIsB[ii] ? Bs[buf] : As[buf]) + sI[ii]*512;
            auto g1 = (const __attribute__((address_space(1))) unsigned int*)(src);
            auto l3 = (__attribute__((address_space(3))) unsigned int*)(uintptr_t)(dst);
            __builtin_amdgcn_global_load_lds(g1, l3, 16, 0, 0);
        }
    };

    const int wm = (w >> 1) * 32, wn = (w & 1) * 32;
    const int lr = lane & 15, lk = lane >> 4;
    int aoff[2][2], boff[2][2];
    #pragma unroll
    for (int mi = 0; mi < 2; ++mi)
        #pragma unroll
        for (int kw = 0; kw < 2; ++kw) {
            int ar = wm + mi*16 + lr;
            aoff[mi][kw] = ar*128 + ((kw*64 + lk*16) ^ ((ar & 7) << 4));
            int br = wn + mi*16 + lr;
            boff[mi][kw] = br*128 + ((kw*64 + lk*16) ^ ((br & 7) << 4));
        }

    f32x4 acc[2][2] = {};
    stage(0, 0);
    const int nk = K >> 6;
    int cur = 0;
    for (int kt = 0; kt < nk; ++kt) {
        __syncthreads();
        if (kt + 1 < nk) stage(cur ^ 1, (kt + 1) << 6);
        const char* Ab = (const char*)As[cur];
        const char* Bb = (const char*)Bs[cur];
        bf16x8 af[2][2], bfv[2][2];
        #pragma unroll
        for (int mi = 0; mi < 2; ++mi)
            #pragma unroll
            for (int kw = 0; kw < 2; ++kw) {
                af[mi][kw]  = *(const bf16x8*)(Ab + aoff[mi][kw]);
                bfv[mi][kw] = *(const bf16x8*)(Bb + boff[mi][kw]);
            }
        #pragma unroll
        for (int kw = 0; kw < 2; ++kw)
            #pragma unroll
            for (int mi = 0; mi < 2; ++mi)
                #pragma unroll
                for (int ni = 0; ni < 2; ++ni)
                    acc[mi][ni] = __builtin_amdgcn_mfma_f32_16x16x32_bf16(
                        af[mi][kw], bfv[ni][kw], acc[mi][ni], 0, 0, 0);
        cur ^= 1;
    }

    const int epi = g.epi[bz], obf = g.obf[bz];
    const float* p1 = g.p1[bz];
    const float* p2 = g.p2[bz];
    float* Cf = (float*)g.C[bz];
    unsigned short* Ch = (unsigned short*)g.C[bz];
    #pragma unroll
    for (int mi = 0; mi < 2; ++mi) {
        #pragma unroll
        for (int ni = 0; ni < 2; ++ni) {
            #pragma unroll
            for (int j = 0; j < 4; ++j) {
                int gm = m0 + wm + mi*16 + lk*4 + j;
                int gn = n0 + wn + ni*16 + lr;
                if (gn >= N) continue;
                size_t idx = (size_t)gm * N + gn;
                float a = acc[mi][ni][j];
                float o = a;
                if (epi == EPI_TANH)        o = tanhf(a);
                else if (epi == EPI_SILU)   o = a / (1.f + expf(-a));
                else if (epi == EPI_RELU2)  { float r = fmaxf(a, 0.f); o = r*r; }
                else if (epi == EPI_WLOG) {
                    float z = -(p1[gn] + a);
                    float sp = (z > 15.f) ? z : log1pf(expf(z));
                    o = logf(fminf(fmaxf(sp, 1e-6f), 1.f));
                }
                else if (epi == EPI_ADDRES) o = a + p1[idx];
                else if (epi == EPI_SIGMUL) o = p2[idx] + p1[idx] / (1.f + expf(-a));
                if (obf) Ch[idx] = f2bf(o); else Cf[idx] = o;
            }
        }
    }
}

// ---------------- chunkwise pass 1: per-(bh,chunk) local work ----------------
// Emits: ypart = Yintra + BF*Yloc (f32, into ybuf), U = KA^T@VX (f32),
//        B63[k] (f32), RD bf16 swizzled LDS image, BF bf16 (linear).
#define SWZI(r, c)  (((r) << 6) + ((c) ^ (((r) & 7) << 3)))           // ushort units
#define FIDX(r, kw) (((r) << 6) + ((((kw)*32) + fk*8) ^ (((r) & 7) << 3)))
__global__ __launch_bounds__(256) void chunk1_k(
    const unsigned short* __restrict__ rb, const unsigned short* __restrict__ kb,
    const unsigned short* __restrict__ vb, const float* __restrict__ wb,
    const float* __restrict__ faaaa,
    float* __restrict__ ypart, float* __restrict__ Ug,
    unsigned short* __restrict__ RDimg, unsigned short* __restrict__ BFb,
    float* __restrict__ B63g)
{
    const int blk = blockIdx.x;           // bh*8 + nc
    const int bh = blk >> 3, nc = blk & 7;
    const int b = bh >> 4, h = bh & 15;
    const int tid = threadIdx.x;
    const int l = tid & 63, w = tid >> 6;
    const int jl = l, q = w;
    const int fr = l & 15, fk = l >> 4;
    const int wm = (w >> 1) * 32, wn = (w & 1) * 32;
    const int t0 = nc * 64;

    __shared__ float sA [64*68];
    __shared__ float sPP[64*68];
    __shared__ float sUD[64];
    __shared__ float sQS[4][64];
    __shared__ __align__(16) unsigned short sRDb [4096];
    __shared__ __align__(16) unsigned short sKAb [4096];
    __shared__ __align__(16) unsigned short sKA2b[4096];
    __shared__ __align__(16) unsigned short sKATb[4096];
    __shared__ __align__(16) unsigned short sVTb [4096];
    __shared__ __align__(16) unsigned short sVXTb[4096];
    __shared__ __align__(16) unsigned short sQMb [4096];
    __shared__ __align__(16) unsigned short sPMb [4096];

    const float u_reg = faaaa[h*64 + jl];
    const size_t base = (size_t)b*T_*E_ + (size_t)h*64;
    const size_t coff = (size_t)blk * 4096;

    float vreg[16];
    // A1: A = cumsum_t(wlog)
    {
        float loc[16]; float cum = 0.f;
        #pragma unroll
        for (int c = 0; c < 16; ++c) {
            float wv = wb[base + (size_t)(t0 + q*16 + c)*E_ + jl];
            cum += wv; loc[c] = cum;
        }
        sQS[q][jl] = cum;
        __syncthreads();
        float pre = 0.f;
        for (int qq = 0; qq < q; ++qq) pre += sQS[qq][jl];
        #pragma unroll
        for (int c = 0; c < 16; ++c) sA[(q*16 + c)*68 + jl] = loc[c] + pre;
    }
    __syncthreads();

    // A2: RD/KA/KA2/KAT/VT + r*u*k staging
    {
        const float atot = sA[63*68 + jl];
        #pragma unroll
        for (int c = 0; c < 16; ++c) {
            const int t = q*16 + c;
            const size_t gi = base + (size_t)(t0 + t)*E_ + jl;
            const float rv = bf2f(rb[gi]), kv = bf2f(kb[gi]), vv = bf2f(vb[gi]);
            vreg[c] = vv;
            const float a = sA[t*68 + jl];
            const float aprev = (t > 0) ? sA[(t-1)*68 + jl] : 0.f;
            sRDb [SWZI(t, jl)] = f2bf(rv * expf(aprev));
            const float ka = kv * expf(atot - a);
            sKAb [SWZI(t, jl)] = f2bf(ka);
            sKA2b[SWZI(t, jl)] = f2bf(kv * expf(-a));
            sKATb[SWZI(jl, t)] = f2bf(ka);
            sVTb [SWZI(jl, t)] = f2bf(vv);
            sPP[t*68 + jl] = rv * u_reg * kv;
        }
    }
    __syncthreads();

    // udiag
    {
        int row = q*16 + (l & 15);
        const float* pp = &sPP[row*68 + (l >> 4)*16];
        float s = 0.f;
        #pragma unroll
        for (int e = 0; e < 16; ++e) s += pp[e];
        s += __shfl_down(s, 16);
        s += __shfl_down(s, 32);
        if ((l >> 4) == 0) sUD[row] = s;
    }

    // B: Q = RD@KA2^T, P = RD@KA^T
    f32x4 accQ[2][2] = {}, accP[2][2] = {};
    #pragma unroll
    for (int kw = 0; kw < 2; ++kw) {
        bf16x8 ar[2], bka[2], bk2[2];
        #pragma unroll
        for (int mi = 0; mi < 2; ++mi)
            ar[mi] = *(const bf16x8*)(&sRDb[FIDX(wm + mi*16 + fr, kw)]);
        #pragma unroll
        for (int ni = 0; ni < 2; ++ni) {
            bka[ni] = *(const bf16x8*)(&sKAb [FIDX(wn + ni*16 + fr, kw)]);
            bk2[ni] = *(const bf16x8*)(&sKA2b[FIDX(wn + ni*16 + fr, kw)]);
        }
        #pragma unroll
        for (int mi = 0; mi < 2; ++mi)
            #pragma unroll
            for (int ni = 0; ni < 2; ++ni) {
                accQ[mi][ni] = __builtin_amdgcn_mfma_f32_16x16x32_bf16(ar[mi], bk2[ni], accQ[mi][ni], 0,0,0);
                accP[mi][ni] = __builtin_amdgcn_mfma_f32_16x16x32_bf16(ar[mi], bka[ni], accP[mi][ni], 0,0,0);
            }
    }
    __syncthreads();

    // mask -> QM (tril-1 + udiag), PM (tril-1)
    #pragma unroll
    for (int mi = 0; mi < 2; ++mi)
        #pragma unroll
        for (int ni = 0; ni < 2; ++ni)
            #pragma unroll
            for (int reg = 0; reg < 4; ++reg) {
                int t = wm + mi*16 + fk*4 + reg;
                int s = wn + ni*16 + fr;
                float qv = (s < t) ? accQ[mi][ni][reg] : ((s == t) ? sUD[t] : 0.f);
                float pv = (s < t) ? accP[mi][ni][reg] : 0.f;
                sQMb[SWZI(t, s)] = f2bf(qv);
                sPMb[SWZI(t, s)] = f2bf(pv);
            }

    // C: Bcum = cumsum_t(A); sA <- BF (also global bf16); VXT; B63
    {
        float loc2[16]; float cum2 = 0.f;
        #pragma unroll
        for (int c = 0; c < 16; ++c) {
            cum2 += sA[(q*16 + c)*68 + jl];
            loc2[c] = cum2;
        }
        sQS[q][jl] = cum2;
        __syncthreads();
        float pre2 = 0.f;
        for (int qq = 0; qq < q; ++qq) pre2 += sQS[qq][jl];
        #pragma unroll
        for (int c = 0; c < 16; ++c) {
            const int t = q*16 + c;
            const float Bv = loc2[c] + pre2;
            const float Bprev = (c > 0) ? (loc2[c-1] + pre2) : pre2;
            const float bfv = expf(Bprev);
            sA[t*68 + jl] = bfv;
            BFb[coff + t*64 + jl] = f2bf(bfv);
            sVXTb[SWZI(jl, t)] = f2bf(vreg[c] * expf(-Bv));
            if (t == 63) B63g[(size_t)blk*64 + jl] = expf(Bv);
        }
    }
    __syncthreads();

    // D: Yintra(QM,VT) + Yloc(PM,VXT) + U(KAT,VXT)
    {
        f32x4 accI[2][2] = {}, accL[2][2] = {}, accU[2][2] = {};
        #pragma unroll
        for (int kw = 0; kw < 2; ++kw) {
            bf16x8 aQ[2], aP[2], aK[2], bV[2], bX[2];
            #pragma unroll
            for (int mi = 0; mi < 2; ++mi) {
                int rA = wm + mi*16 + fr;
                aQ[mi] = *(const bf16x8*)(&sQMb [FIDX(rA, kw)]);
                aP[mi] = *(const bf16x8*)(&sPMb [FIDX(rA, kw)]);
                aK[mi] = *(const bf16x8*)(&sKATb[FIDX(rA, kw)]);
            }
            #pragma unroll
            for (int ni = 0; ni < 2; ++ni) {
                int rB = wn + ni*16 + fr;
                bV[ni] = *(const bf16x8*)(&sVTb [FIDX(rB, kw)]);
                bX[ni] = *(const bf16x8*)(&sVXTb[FIDX(rB, kw)]);
            }
            #pragma unroll
            for (int mi = 0; mi < 2; ++mi)
                #pragma unroll
                for (int ni = 0; ni < 2; ++ni) {
                    accI[mi][ni] = __builtin_amdgcn_mfma_f32_16x16x32_bf16(aQ[mi], bV[ni], accI[mi][ni], 0,0,0);
                    accL[mi][ni] = __builtin_amdgcn_mfma_f32_16x16x32_bf16(aP[mi], bX[ni], accL[mi][ni], 0,0,0);
                    accU[mi][ni] = __builtin_amdgcn_mfma_f32_16x16x32_bf16(aK[mi], bX[ni], accU[mi][ni], 0,0,0);
                }
        }
        // ypart = Yintra + BF*Yloc;  U out
        #pragma unroll
        for (int mi = 0; mi < 2; ++mi)
            #pragma unroll
            for (int ni = 0; ni < 2; ++ni)
                #pragma unroll
                for (int reg = 0; reg < 4; ++reg) {
                    int t = wm + mi*16 + fk*4 + reg;
                    int k = wn + ni*16 + fr;
                    float bfv = sA[t*68 + k];
                    ypart[base + (size_t)(t0 + t)*E_ + k] = accI[mi][ni][reg] + bfv*accL[mi][ni][reg];
                    Ug[coff + t*64 + k] = accU[mi][ni][reg];   // here t is the j index
                }
    }
    // dump swizzled RD image
    for (int i = tid; i < 512; i += 256)
        ((bf16x8*)(RDimg + coff))[i] = ((const bf16x8*)sRDb)[i];
}

// ---------------- chunkwise pass 2: sequential state scan (tiny) ----------------
__global__ __launch_bounds__(256) void chunk2_k(
    const float* __restrict__ st_in, const float* __restrict__ Ug,
    const float* __restrict__ B63g,
    unsigned short* __restrict__ Simg, float* __restrict__ st_out)
{
    const int bh = blockIdx.x;
    const int tid = threadIdx.x;
    __shared__ float S[4096];
    for (int i = tid; i < 4096; i += 256) S[i] = st_in[(size_t)bh*4096 + i];
    __syncthreads();
    const int k = tid >> 2, j0 = (tid & 3) * 16;
    for (int nc = 0; nc < 8; ++nc) {
        const size_t coff = ((size_t)bh*8 + nc) * 4096;
        #pragma unroll
        for (int hf = 0; hf < 2; ++hf) {
            bf16x8 tmp;
            #pragma unroll
            for (int e = 0; e < 8; ++e) tmp[e] = (short)f2bf(S[(j0 + hf*8 + e)*64 + k]);
            *(bf16x8*)(&Simg[coff + SWZI(k, j0 + hf*8)]) = tmp;
        }
        __syncthreads();
        for (int i = tid; i < 4096; i += 256) {
            int kk = i & 63;
            S[i] = B63g[((size_t)bh*8 + nc)*64 + kk] * (S[i] + Ug[coff + i]);
        }
        __syncthreads();
    }
    for (int i = tid; i < 4096; i += 256) st_out[(size_t)bh*4096 + i] = S[i];
}

// ---------------- chunkwise pass 3: y += BF * (RD @ S_prev) ----------------
__global__ __launch_bounds__(256) void chunk3_k(
    const unsigned short* __restrict__ RDimg, const unsigned short* __restrict__ Simg,
    const unsigned short* __restrict__ BFb, float* __restrict__ yb)
{
    const int blk = blockIdx.x;           // bh*8 + nc
    const int bh = blk >> 3, nc = blk & 7;
    const int b = bh >> 4, h = bh & 15;
    const int tid = threadIdx.x;
    const int l = tid & 63, w = tid >> 6;
    const int fr = l & 15, fk = l >> 4;
    const int wm = (w >> 1) * 32, wn = (w & 1) * 32;
    const int t0 = nc * 64;
    __shared__ __align__(16) unsigned short sRDb[4096];
    __shared__ __align__(16) unsigned short sSTb[4096];
    const size_t coff = (size_t)blk * 4096;

    #pragma unroll
    for (int ii = 0; ii < 2; ++ii) {
        int seg = (w*2 + ii) * 512;       // 64 lanes * 8 ushorts
        {
            auto g1 = (const __attribute__((address_space(1))) unsigned int*)(RDimg + coff + seg + (l << 3));
            auto l3 = (__attribute__((address_space(3))) unsigned int*)(uintptr_t)(sRDb + seg);
            __builtin_amdgcn_global_load_lds(g1, l3, 16, 0, 0);
        }
        {
            auto g1 = (const __attribute__((address_space(1))) unsigned int*)(Simg + coff + seg + (l << 3));
            auto l3 = (__attribute__((address_space(3))) unsigned int*)(uintptr_t)(sSTb + seg);
            __builtin_amdgcn_global_load_lds(g1, l3, 16, 0, 0);
        }
    }
    __syncthreads();

    f32x4 accS[2][2] = {};
    #pragma unroll
    for (int kw = 0; kw < 2; ++kw) {
        bf16x8 aR[2], bS[2];
        #pragma unroll
        for (int mi = 0; mi < 2; ++mi)
            aR[mi] = *(const bf16x8*)(&sRDb[FIDX(wm + mi*16 + fr, kw)]);
        #pragma unroll
        for (int ni = 0; ni < 2; ++ni)
            bS[ni] = *(const bf16x8*)(&sSTb[FIDX(wn + ni*16 + fr, kw)]);
        #pragma unroll
        for (int mi = 0; mi < 2; ++mi)
            #pragma unroll
            for (int ni = 0; ni < 2; ++ni)
                accS[mi][ni] = __builtin_amdgcn_mfma_f32_16x16x32_bf16(aR[mi], bS[ni], accS[mi][ni], 0,0,0);
    }
    const size_t base = (size_t)b*T_*E_ + (size_t)h*64;
    #pragma unroll
    for (int mi = 0; mi < 2; ++mi)
        #pragma unroll
        for (int ni = 0; ni < 2; ++ni)
            #pragma unroll
            for (int reg = 0; reg < 4; ++reg) {
                int t = wm + mi*16 + fk*4 + reg;
                int k = wn + ni*16 + fr;
                size_t gp = base + (size_t)(t0 + t)*E_ + k;
                yb[gp] += bf2f(BFb[coff + t*64 + k]) * accS[mi][ni][reg];
            }
}

// ---------------- GroupNorm (global stats per head) ----------------
__global__ __launch_bounds__(256) void gn_stats_k(const float* __restrict__ y,
        float* __restrict__ part)
{
    const int h = blockIdx.x, slab = blockIdx.y;
    const int tid = threadIdx.x;
    float s = 0.f, ss = 0.f;
    for (int i = tid; i < 2048; i += 256) {
        int r = slab*32 + (i >> 6), k = i & 63;
        float v = y[(size_t)r*E_ + h*64 + k];
        s += v; ss += v*v;
    }
    #pragma unroll
    for (int off = 32; off > 0; off >>= 1) {
        s  += __shfl_down(s, off);
        ss += __shfl_down(ss, off);
    }
    __shared__ float ps[4], pss[4];
    if ((tid & 63) == 0) { ps[tid>>6] = s; pss[tid>>6] = ss; }
    __syncthreads();
    if (tid == 0) {
        part[h*32 + slab]       = ps[0]+ps[1]+ps[2]+ps[3];
        part[512 + h*32 + slab] = pss[0]+pss[1]+pss[2]+pss[3];
    }
}

__global__ __launch_bounds__(256) void gn_reduce_k(const float* __restrict__ part,
        float* __restrict__ stats)
{
    int tid = threadIdx.x;
    if (tid < 16) {
        float s = 0.f, ss = 0.f;
        for (int sl = 0; sl < 32; ++sl) {
            s  += part[tid*32 + sl];
            ss += part[512 + tid*32 + sl];
        }
        float mu  = s * (1.f/65536.f);
        float var = ss * (1.f/65536.f) - mu*mu;
        stats[tid]      = mu;
        stats[16 + tid] = rsqrtf(var + 1e-5f);
    }
}

__global__ __launch_bounds__(256) void gn_apply_k(const float* __restrict__ y,
        const float* __restrict__ g, const float* __restrict__ stats,
        const float* __restrict__ sc, const float* __restrict__ bi,
        unsigned short* __restrict__ z)
{
    int idx = blockIdx.x*256 + threadIdx.x;
    int d = idx & 1023;
    int h = d >> 6;
    float mu = stats[h], rstd = stats[16 + h];
    float yn = (y[idx] - mu)*rstd*sc[d] + bi[d];
    z[idx] = f2bf(yn * g[idx]);
}

// ---------------- launch ----------------
extern "C" void kernel_launch(void* const* d_in, const int* in_sizes, int n_in,
                              void* d_out, int out_size, void* d_ws, size_t ws_size,
                              hipStream_t stream)
{
    const float* x       = (const float*)d_in[0];
    const float* state0  = (const float*)d_in[1];
    const float* maa_x   = (const float*)d_in[2];
    const float* maa_w   = (const float*)d_in[3];
    const float* maa_k   = (const float*)d_in[4];
    const float* maa_v   = (const float*)d_in[5];
    const float* maa_r   = (const float*)d_in[6];
    const float* maa_g   = (const float*)d_in[7];
    const float* tdecay  = (const float*)d_in[8];
    const float* faaaa   = (const float*)d_in[9];
    const float* w1      = (const float*)d_in[10];
    const float* w2      = (const float*)d_in[11];
    const float* dw1     = (const float*)d_in[12];
    const float* dw2     = (const float*)d_in[13];
    const float* Wr      = (const float*)d_in[14];
    const float* Wk      = (const float*)d_in[15];
    const float* Wv      = (const float*)d_in[16];
    const float* Wg      = (const float*)d_in[17];
    const float* Wo      = (const float*)d_in[18];
    const float* lnx_s   = (const float*)d_in[19];
    const float* lnx_b   = (const float*)d_in[20];
    const float* maa_kch = (const float*)d_in[21];
    const float* maa_rch = (const float*)d_in[22];
    const float* Wk_ch   = (const float*)d_in[23];
    const float* Wv_ch   = (const float*)d_in[24];
    const float* Wr_ch   = (const float*)d_in[25];
    const float* ln1_s   = (const float*)d_in[26];
    const float* ln1_b   = (const float*)d_in[27];
    const float* ln2_s   = (const float*)d_in[28];
    const float* ln2_b   = (const float*)d_in[29];

    // ---- workspace layout (f32 block) ----
    float* xn     = (float*)d_ws;               // 1M (reused as xn2)
    float* t5     = xn + 1048576;               // 163840
    float* gbuf   = t5 + 163840;                // 1M
    float* wlogb  = gbuf + 1048576;             // 1M  (alias: mb16 start)
    float* ybuf   = wlogb + 1048576;            // 1M
    float* kvb    = ybuf + 1048576;             // 1M
    float* gnpart = kvb + 1048576;              // 1024
    float* gnstat = gnpart + 1024;              // 32
    float* b63g   = gnstat + 32;                // 16384 (256*64)
    // ---- ushort block ----
    unsigned short* u = (unsigned short*)(b63g + 16384);
    unsigned short* xmix = u;  u += 1048576;    // reused: BFb, then zbuf
    unsigned short* xw   = u;  u += 1048576;    // reused as ak
    unsigned short* xk   = u;  u += 1048576;    // reused as ar
    unsigned short* xv_  = u;  u += 1048576;    // reused: Ug lo / kk[0:1M]
    unsigned short* xr   = u;  u += 1048576;    // reused: Ug hi / kk[1M:2M]
    unsigned short* xg   = u;  u += 1048576;    // reused: RDimg / kk[2M:3M]
    unsigned short* xtr  = u;  u += 1048576;    // reused: Simg  / kk[3M:4M]
    unsigned short* rb   = u;  u += 1048576;
    unsigned short* kb   = u;  u += 1048576;
    unsigned short* vb   = u;  u += 1048576;
    unsigned short* hdecb= u;  u += 65536;
    unsigned short* WrT  = u;  u += 1048576;
    unsigned short* WkT  = u;  u += 1048576;
    unsigned short* WvT  = u;  u += 1048576;
    unsigned short* WgT  = u;  u += 1048576;
    unsigned short* WoT  = u;  u += 1048576;
    unsigned short* WrchT= u;  u += 1048576;
    unsigned short* WkchT= u;  u += 4194304;    // 4096 x 1024
    unsigned short* WvchT= u;  u += 4194304;    // 1024 x 4096
    unsigned short* w1T  = u;  u += 196608;     // 192 x 1024
    unsigned short* dw1T = u;  u += 65536;      // 64 x 1024
    unsigned short* dw2T = u;  u += 65536;      // 1024 x 64
    unsigned short* W2T5 = u;  u += 327680;     // 5 x 1024 x 64
    unsigned short* t5p  = u;  u += 327680;     // 5 x 1024 x 64
    // aliases
    unsigned short* zbuf  = xmix;
    unsigned short* akb   = xw;
    unsigned short* arb   = xk;
    unsigned short* kkb   = xv_;                // 4M contiguous
    unsigned short* mb16  = (unsigned short*)wlogb;   // 5M ushort over wlogb..kvb
    float*          Ug    = (float*)xv_;        // 1M f32 (xv_+xr)
    unsigned short* RDimg = xg;
    unsigned short* Simg  = xtr;
    unsigned short* BFb   = xmix;

    float* out   = (float*)d_out;
    float* x2buf = out;
    float* stout = out + (size_t)BTE;

    // ---- weight convert+transpose (once per launch) ----
    {
        TransArgs ta{}; ta.K = 1024; ta.N = 1024; ta.Npad = 1024; ta.Kpad = 1024;
        ta.src[0]=Wr; ta.src[1]=Wk; ta.src[2]=Wv; ta.src[3]=Wg; ta.src[4]=Wo; ta.src[5]=Wr_ch;
        ta.dst[0]=WrT; ta.dst[1]=WkT; ta.dst[2]=WvT; ta.dst[3]=WgT; ta.dst[4]=WoT; ta.dst[5]=WrchT;
        wtrans_k<<<dim3(16,16,6), 256, 0, stream>>>(ta);
    }
    { TransArgs ta{}; ta.K=1024; ta.N=4096; ta.Npad=4096; ta.Kpad=1024; ta.src[0]=Wk_ch; ta.dst[0]=WkchT;
      wtrans_k<<<dim3(64,16,1), 256, 0, stream>>>(ta); }
    { TransArgs ta{}; ta.K=4096; ta.N=1024; ta.Npad=1024; ta.Kpad=4096; ta.src[0]=Wv_ch; ta.dst[0]=WvchT;
      wtrans_k<<<dim3(16,64,1), 256, 0, stream>>>(ta); }
    { TransArgs ta{}; ta.K=1024; ta.N=160; ta.Npad=192; ta.Kpad=1024; ta.src[0]=w1; ta.dst[0]=w1T;
      wtrans_k<<<dim3(3,16,1), 256, 0, stream>>>(ta); }
    { TransArgs ta{}; ta.K=1024; ta.N=64; ta.Npad=64; ta.Kpad=1024; ta.src[0]=dw1; ta.dst[0]=dw1T;
      wtrans_k<<<dim3(1,16,1), 256, 0, stream>>>(ta); }
    { TransArgs ta{}; ta.K=64; ta.N=1024; ta.Npad=1024; ta.Kpad=64; ta.src[0]=dw2; ta.dst[0]=dw2T;
      wtrans_k<<<dim3(16,1,1), 256, 0, stream>>>(ta); }
    { TransArgs ta{}; ta.K=32; ta.N=1024; ta.Npad=1024; ta.Kpad=64;
      for (int z = 0; z < 5; ++z) { ta.src[z]=w2 + (size_t)z*32768; ta.dst[z]=W2T5 + (size_t)z*65536; }
      wtrans_k<<<dim3(16,1,5), 256, 0, stream>>>(ta); }

    // ---- time mixing ----
    ln_rows_k<<<1024, 256, 0, stream>>>(x, ln1_s, ln1_b, xn);
    mix_x_k<<<4096, 256, 0, stream>>>(xn, maa_x, xmix);
    { GemmArgs g{}; g.M=1024; g.N=160; g.K=1024;
      g.A[0]=xmix; g.B[0]=w1T; g.C[0]=t5; g.epi[0]=EPI_TANH; g.obf[0]=0;
      mgemm_k<<<dim3(3,16,1), 256, 0, stream>>>(g); }
    t5repack_k<<<1280, 256, 0, stream>>>(t5, t5p);
    { GemmArgs g{}; g.M=1024; g.N=1024; g.K=64;
      for (int z = 0; z < 5; ++z) {
          g.A[z]=t5p + (size_t)z*65536; g.B[z]=W2T5 + (size_t)z*65536;
          g.C[z]=mb16 + (size_t)z*1048576; g.epi[z]=EPI_NONE; g.obf[z]=1;
      }
      mgemm_k<<<dim3(16,16,5), 256, 0, stream>>>(g); }
    mix5_apply_k<<<4096, 256, 0, stream>>>(xn, mb16, maa_w, maa_k, maa_v, maa_r, maa_g,
                                           xw, xk, xv_, xr, xg);
    { GemmArgs g{}; g.M=1024; g.N=1024; g.K=1024;
      g.A[0]=xr;  g.B[0]=WrT; g.C[0]=rb;   g.epi[0]=EPI_NONE; g.obf[0]=1;
      g.A[1]=xk;  g.B[1]=WkT; g.C[1]=kb;   g.epi[1]=EPI_NONE; g.obf[1]=1;
      g.A[2]=xv_; g.B[2]=WvT; g.C[2]=vb;   g.epi[2]=EPI_NONE; g.obf[2]=1;
      g.A[3]=xg;  g.B[3]=WgT; g.C[3]=gbuf; g.epi[3]=EPI_SILU; g.obf[3]=0;
      mgemm_k<<<dim3(16,16,4), 256, 0, stream>>>(g); }
    { GemmArgs g{}; g.M=1024; g.N=64; g.K=1024;
      g.A[0]=xw; g.B[0]=dw1T; g.C[0]=hdecb; g.epi[0]=EPI_TANH; g.obf[0]=1;
      mgemm_k<<<dim3(1,16,1), 256, 0, stream>>>(g); }
    { GemmArgs g{}; g.M=1024; g.N=1024; g.K=64;
      g.A[0]=hdecb; g.B[0]=dw2T; g.C[0]=wlogb; g.epi[0]=EPI_WLOG; g.obf[0]=0; g.p1[0]=tdecay;
      mgemm_k<<<dim3(16,16,1), 256, 0, stream>>>(g); }

    // chunkwise: parallel pass1 -> tiny scan -> parallel pass2
    chunk1_k<<<256, 256, 0, stream>>>(rb, kb, vb, wlogb, faaaa, ybuf, Ug, RDimg, BFb, b63g);
    chunk2_k<<<32, 256, 0, stream>>>(state0, Ug, b63g, Simg, stout);
    chunk3_k<<<256, 256, 0, stream>>>(RDimg, Simg, BFb, ybuf);

    gn_stats_k<<<dim3(16,32), 256, 0, stream>>>(ybuf, gnpart);
    gn_reduce_k<<<1, 256, 0, stream>>>(gnpart, gnstat);
    gn_apply_k<<<4096, 256, 0, stream>>>(ybuf, gbuf, gnstat, lnx_s, lnx_b, zbuf);
    { GemmArgs g{}; g.M=1024; g.N=1024; g.K=1024;
      g.A[0]=zbuf; g.B[0]=WoT; g.C[0]=x2buf; g.epi[0]=EPI_ADDRES; g.obf[0]=0; g.p1[0]=x;
      mgemm_k<<<dim3(16,16,1), 256, 0, stream>>>(g); }

    // ---- channel mixing ----
    ln_rows_k<<<1024, 256, 0, stream>>>(x2buf, ln2_s, ln2_b, xn);
    mix_ch_k<<<4096, 256, 0, stream>>>(xn, maa_kch, maa_rch, akb, arb);
    { GemmArgs g{}; g.M=1024; g.N=4096; g.K=1024;
      g.A[0]=akb; g.B[0]=WkchT; g.C[0]=kkb; g.epi[0]=EPI_RELU2; g.obf[0]=1;
      mgemm_k<<<dim3(64,16,1), 256, 0, stream>>>(g); }
    { GemmArgs g{}; g.M=1024; g.N=1024; g.K=4096;
      g.A[0]=kkb; g.B[0]=WvchT; g.C[0]=kvb; g.epi[0]=EPI_NONE; g.obf[0]=0;
      mgemm_k<<<dim3(16,16,1), 256, 0, stream>>>(g); }
    { GemmArgs g{}; g.M=1024; g.N=1024; g.K=1024;
      g.A[0]=arb; g.B[0]=WrchT; g.C[0]=out; g.epi[0]=EPI_SIGMUL; g.obf[0]=0;
      g.p1[0]=kvb; g.p2[0]=x2buf;
      mgemm_k<<<dim3(16,16,1), 256, 0, stream>>>(g); }
}